// Round 1
// baseline (869.427 us; speedup 1.0000x reference)
//
#include <hip/hip_runtime.h>
#include <hip/hip_bf16.h>
#include <math.h>

#define BSZ 2
#define LSEQ 2048
#define DMODEL 512
#define DINNER 1024
#define NST 16
#define RDT 32
#define GDBL 64   // RDT + 2*NST

__device__ __forceinline__ float siluf(float x){ return x / (1.f + __expf(-x)); }
__device__ __forceinline__ float softplusf(float x){
  return (x > 20.f) ? x : log1pf(__expf(x));
}

// 16-lane-row sum via DPP row_shr (VALU pipe, no LDS). Result valid in lane n==0 of each 16-lane row.
__device__ __forceinline__ float red16(float p){
  int t;
  t = __builtin_amdgcn_update_dpp(0, __float_as_int(p), 0x118, 0xf, 0xf, true); p += __int_as_float(t);
  t = __builtin_amdgcn_update_dpp(0, __float_as_int(p), 0x114, 0xf, 0xf, true); p += __int_as_float(t);
  t = __builtin_amdgcn_update_dpp(0, __float_as_int(p), 0x112, 0xf, 0xf, true); p += __int_as_float(t);
  t = __builtin_amdgcn_update_dpp(0, __float_as_int(p), 0x111, 0xf, 0xf, true); p += __int_as_float(t);
  return p;
}

// ---------------- K1: LN1 stats (mu, rstd per (b,l)) ----------------
// grid: BSZ*(LSEQ/32) = 128, block 256. Coalesced over l; each thread sums 64 d's.
__global__ void k1_ln_stats(const float* __restrict__ x, float* __restrict__ mu, float* __restrict__ rs){
  int blk = blockIdx.x;
  int b = blk / (LSEQ/32);
  int l0 = (blk % (LSEQ/32)) * 32;
  int t = threadIdx.x;
  int lc = t & 31, dc = t >> 5;
  const float* xb = x + (size_t)b*DMODEL*LSEQ;
  float s=0.f, q=0.f;
  for (int d = dc*64; d < dc*64+64; ++d){
    float v = xb[(size_t)d*LSEQ + l0 + lc];
    s += v; q += v*v;
  }
  __shared__ float ss[8][33], qq[8][33];
  ss[dc][lc]=s; qq[dc][lc]=q;
  __syncthreads();
  if (t < 32){
    float S=0.f,Q=0.f;
    for (int i=0;i<8;++i){S+=ss[i][t];Q+=qq[i][t];}
    float m = S/DMODEL;
    float var = Q/DMODEL - m*m;
    mu[b*LSEQ+l0+t]=m;
    rs[b*LSEQ+l0+t]=rsqrtf(var+1e-5f);
  }
}

// ---------------- K2: in_proj GEMM with fused LN1 on A ----------------
// xz[m][e] = sum_d xn[m][d]*Wip[e][d];  m=(b,l).  A[m][k]=xn from x (stride-1 in l).
// grid (2048/128=16, 4096/128=32), block 256, 128x128 tile, 8x8 per thread.
__global__ __launch_bounds__(256) void k2_inproj(
    const float* __restrict__ x, const float* __restrict__ mu, const float* __restrict__ rs,
    const float* __restrict__ w1, const float* __restrict__ b1, const float* __restrict__ W,
    float* __restrict__ xin, float* __restrict__ z){
  __shared__ float As[8][128];
  __shared__ float Bs[8][130];
  __shared__ float mus[128], rss[128];
  int t = threadIdx.x;
  int n0 = blockIdx.x * 128;
  int m0 = blockIdx.y * 128;
  int b  = m0 >> 11;
  int l0 = m0 & (LSEQ-1);
  if (t < 128){ mus[t]=mu[m0+t]; rss[t]=rs[m0+t]; }
  int tx = t & 15, ty = t >> 4;
  float acc[8][8];
  #pragma unroll
  for(int i=0;i<8;i++){
    #pragma unroll
    for(int j=0;j<8;j++) acc[i][j]=0.f;
  }
  int akk = t >> 5;         // 0..7 (k row)
  int ac4 = (t & 31) * 4;   // m col
  int bn  = t & 127;        // n
  int bk4 = (t >> 7) * 4;   // 0 or 4
  __syncthreads();
  for (int k0 = 0; k0 < DMODEL; k0 += 8){
    float4 v = *(const float4*)&x[((size_t)(b*DMODEL + k0 + akk))*LSEQ + l0 + ac4];
    float w1v = w1[k0+akk], b1v = b1[k0+akk];
    As[akk][ac4+0] = (v.x - mus[ac4+0])*rss[ac4+0]*w1v + b1v;
    As[akk][ac4+1] = (v.y - mus[ac4+1])*rss[ac4+1]*w1v + b1v;
    As[akk][ac4+2] = (v.z - mus[ac4+2])*rss[ac4+2]*w1v + b1v;
    As[akk][ac4+3] = (v.w - mus[ac4+3])*rss[ac4+3]*w1v + b1v;
    float4 wv = *(const float4*)&W[(size_t)(n0+bn)*DMODEL + k0 + bk4];
    Bs[bk4+0][bn]=wv.x; Bs[bk4+1][bn]=wv.y; Bs[bk4+2][bn]=wv.z; Bs[bk4+3][bn]=wv.w;
    __syncthreads();
    #pragma unroll
    for (int kk=0;kk<8;++kk){
      float a[8], bb[8];
      #pragma unroll
      for (int i=0;i<8;i++) a[i]=As[kk][ty*8+i];
      #pragma unroll
      for (int j=0;j<8;j++) bb[j]=Bs[kk][tx*8+j];
      #pragma unroll
      for (int i=0;i<8;i++){
        #pragma unroll
        for (int j=0;j<8;j++) acc[i][j] += a[i]*bb[j];
      }
    }
    __syncthreads();
  }
  bool half = (n0 >= DINNER);
  float* outp = half ? z : xin;
  int col0 = n0 - (half?DINNER:0) + tx*8;
  #pragma unroll
  for (int i=0;i<8;i++){
    int m = m0 + ty*8 + i;
    float* row = outp + (size_t)m*DINNER + col0;
    float4 p0 = make_float4(acc[i][0],acc[i][1],acc[i][2],acc[i][3]);
    float4 p1 = make_float4(acc[i][4],acc[i][5],acc[i][6],acc[i][7]);
    *(float4*)&row[0]=p0; *(float4*)&row[4]=p1;
  }
}

// ---------------- K3: causal depthwise conv (K=4) + SiLU ----------------
// grid: B*L*DINNER/4/256 = 4096, block 256. float4 over e.
__global__ void k3_conv(const float* __restrict__ xin, const float* __restrict__ cw,
                        const float* __restrict__ cb, float* __restrict__ xc){
  int idx = blockIdx.x*blockDim.x + threadIdx.x;
  int e4 = (idx & (DINNER/4 - 1)) * 4;
  int m = idx >> 8;
  int b = m >> 11; int l = m & (LSEQ-1);
  float4 accb = *(const float4*)&cb[e4];
  float acc[4] = {accb.x, accb.y, accb.z, accb.w};
  #pragma unroll
  for (int k=0;k<4;++k){
    int li = l + k - 3;
    if (li >= 0){
      float4 v = *(const float4*)&xin[((size_t)(b*LSEQ+li))*DINNER + e4];
      acc[0] += v.x * cw[(e4+0)*4 + k];
      acc[1] += v.y * cw[(e4+1)*4 + k];
      acc[2] += v.z * cw[(e4+2)*4 + k];
      acc[3] += v.w * cw[(e4+3)*4 + k];
    }
  }
  float4 o;
  o.x = siluf(acc[0]); o.y = siluf(acc[1]); o.z = siluf(acc[2]); o.w = siluf(acc[3]);
  *(float4*)&xc[(size_t)m*DINNER + e4] = o;
}

// ---------------- K4: x_proj (dbl[m][g] = xc[m]·Wxp[g]) ----------------
// thread per (m-group-of-8, g); wave = 64 g's of one m-group -> xc loads broadcast.
// grid: (B*L/8)*64/256 = 128, block 256.
__global__ void k4_xproj(const float* __restrict__ xc, const float* __restrict__ Wxp,
                         float* __restrict__ dblo){
  int idx = blockIdx.x*blockDim.x + threadIdx.x;
  int g = idx & 63; int m0 = (idx >> 6) * 8;
  const float* wr = Wxp + (size_t)g*DINNER;
  float s[8] = {0.f,0.f,0.f,0.f,0.f,0.f,0.f,0.f};
  for (int k=0;k<DINNER;k+=4){
    float4 w = *(const float4*)&wr[k];
    #pragma unroll
    for (int j=0;j<8;++j){
      float4 a = *(const float4*)&xc[(size_t)(m0+j)*DINNER + k];
      s[j] += a.x*w.x + a.y*w.y + a.z*w.z + a.w*w.w;
    }
  }
  #pragma unroll
  for (int j=0;j<8;++j) dblo[(size_t)(m0+j)*GDBL + g] = s[j];
}

// ---------------- K6: fused dt_proj + softplus + selective scan + gate ----------------
// grid: B*(DINNER/16) = 128 blocks, block 256 = 16 d x 16 n. Chunked over L (32 steps/chunk).
// Writes yT laid out (B, DINNER, L) so out_proj's A-load is stride-1 in l.
__global__ __launch_bounds__(256) void k6_scan(
    const float* __restrict__ dblg, const float* __restrict__ xcg, const float* __restrict__ zg,
    const float* __restrict__ Wdt, const float* __restrict__ dtbias,
    const float* __restrict__ Alog, const float* __restrict__ Dp, float* __restrict__ yT){
  int blk = blockIdx.x;
  int b = blk >> 6;
  int d0 = (blk & 63) * 16;
  int t = threadIdx.x;
  int dl = t >> 4, n = t & 15;
  int d = d0 + dl;
  float Adn = -__expf(Alog[d*NST + n]);
  float Dv = Dp[d];
  float h = 0.f;

  __shared__ float dbls[32][36];     // dt_lo part of dbl rows (cols 0..31)
  __shared__ float Wdts[16][33];
  __shared__ float biass[16];
  __shared__ float dts_t[16][36];    // [d][r] transposed for float4-over-r reads
  __shared__ float xcs_t[16][36];
  __shared__ float Bts[16][36];      // [n][r]
  __shared__ float Cts[16][36];
  __shared__ float zs[32][17];       // [r][d]
  __shared__ float ys[16][33];       // [d][r]

  { // preload Wdt tile + bias
    int c = t & 31, rr = t >> 5;     // rr 0..7
    Wdts[rr][c]   = Wdt[(size_t)(d0+rr)*RDT + c];
    Wdts[rr+8][c] = Wdt[(size_t)(d0+rr+8)*RDT + c];
    if (t < 16) biass[t] = dtbias[d0+t];
  }

  for (int l0 = 0; l0 < LSEQ; l0 += 32){
    __syncthreads();   // prev chunk fully consumed (also covers preload on 1st iter)
    { // stage dt_lo rows (float4) + xc/z/B/C (transposed where needed)
      int c4 = (t & 7) * 4;
      int rr = t >> 3;               // 0..31
      float4 v = *(const float4*)&dblg[(size_t)(b*LSEQ + l0 + rr)*GDBL + c4];
      *(float4*)&dbls[rr][c4] = v;
      int c = t & 15;
      int r1 = t >> 4, r2 = r1 + 16;
      size_t row1 = (size_t)(b*LSEQ + l0 + r1);
      size_t row2 = (size_t)(b*LSEQ + l0 + r2);
      xcs_t[c][r1] = xcg[row1*DINNER + d0 + c];
      xcs_t[c][r2] = xcg[row2*DINNER + d0 + c];
      zs[r1][c]    = zg [row1*DINNER + d0 + c];
      zs[r2][c]    = zg [row2*DINNER + d0 + c];
      Bts[c][r1]   = dblg[row1*GDBL + RDT + c];
      Bts[c][r2]   = dblg[row2*GDBL + RDT + c];
      Cts[c][r1]   = dblg[row1*GDBL + RDT + NST + c];
      Cts[c][r2]   = dblg[row2*GDBL + RDT + NST + c];
    }
    __syncthreads();
    { // fused dt_proj: dt[r][c] = softplus(dbl_lo[r]·Wdt[d0+c] + bias)
      int c = t & 15;
      int r1 = t >> 4, r2 = r1 + 16;
      float s1 = biass[c], s2 = biass[c];
      #pragma unroll
      for (int rr=0; rr<RDT; ++rr){
        float w = Wdts[c][rr];
        s1 += dbls[r1][rr] * w;
        s2 += dbls[r2][rr] * w;
      }
      dts_t[c][r1] = softplusf(s1);
      dts_t[c][r2] = softplusf(s2);
    }
    __syncthreads();
    // sequential scan: 32 steps, vector LDS reads every 4 steps, DPP reduce over n
    for (int r0=0; r0<32; r0+=4){
      float4 dt4 = *(const float4*)&dts_t[dl][r0];
      float4 xc4 = *(const float4*)&xcs_t[dl][r0];
      float4 B4  = *(const float4*)&Bts[n][r0];
      float4 C4  = *(const float4*)&Cts[n][r0];
      const float* dtp = (const float*)&dt4;
      const float* xcp = (const float*)&xc4;
      const float* Bp  = (const float*)&B4;
      const float* Cp  = (const float*)&C4;
      #pragma unroll
      for (int j=0;j<4;++j){
        int r = r0 + j;
        float dtv = dtp[j];
        float a = __expf(dtv * Adn);
        h = a*h + dtv * Bp[j] * xcp[j];
        float p = red16(h * Cp[j]);
        if (n == 0){
          float y = p + xcp[j]*Dv;
          ys[dl][r] = y * siluf(zs[r][dl]);
        }
      }
    }
    __syncthreads();
    { // write y chunk, (B, DINNER, L) layout, contiguous over l
      int c = t & 31;
      int rr = t >> 5;   // 0..7
      yT[((size_t)(b*DINNER + d0 + rr))*LSEQ + l0 + c]     = ys[rr][c];
      yT[((size_t)(b*DINNER + d0 + rr + 8))*LSEQ + l0 + c] = ys[rr+8][c];
    }
  }
}

// ---------------- K7: out_proj GEMM ----------------
// xm[m][o] = sum_e yT[b][e][l] * Wop[o][e].  grid (512/128=4, 4096/128=32).
__global__ __launch_bounds__(256) void k7_outproj(
    const float* __restrict__ yT, const float* __restrict__ W, float* __restrict__ xm){
  __shared__ float As[8][128];
  __shared__ float Bs[8][130];
  int t = threadIdx.x;
  int n0 = blockIdx.x * 128;
  int m0 = blockIdx.y * 128;
  int b  = m0 >> 11;
  int l0 = m0 & (LSEQ-1);
  int tx = t & 15, ty = t >> 4;
  float acc[8][8];
  #pragma unroll
  for(int i=0;i<8;i++){
    #pragma unroll
    for(int j=0;j<8;j++) acc[i][j]=0.f;
  }
  int akk = t >> 5;
  int ac4 = (t & 31) * 4;
  int bn  = t & 127;
  int bk4 = (t >> 7) * 4;
  for (int k0 = 0; k0 < DINNER; k0 += 8){
    float4 v = *(const float4*)&yT[((size_t)(b*DINNER + k0 + akk))*LSEQ + l0 + ac4];
    As[akk][ac4+0]=v.x; As[akk][ac4+1]=v.y; As[akk][ac4+2]=v.z; As[akk][ac4+3]=v.w;
    float4 wv = *(const float4*)&W[(size_t)(n0+bn)*DINNER + k0 + bk4];
    Bs[bk4+0][bn]=wv.x; Bs[bk4+1][bn]=wv.y; Bs[bk4+2][bn]=wv.z; Bs[bk4+3][bn]=wv.w;
    __syncthreads();
    #pragma unroll
    for (int kk=0;kk<8;++kk){
      float a[8], bb[8];
      #pragma unroll
      for (int i=0;i<8;i++) a[i]=As[kk][ty*8+i];
      #pragma unroll
      for (int j=0;j<8;j++) bb[j]=Bs[kk][tx*8+j];
      #pragma unroll
      for (int i=0;i<8;i++){
        #pragma unroll
        for (int j=0;j<8;j++) acc[i][j] += a[i]*bb[j];
      }
    }
    __syncthreads();
  }
  int col0 = n0 + tx*8;
  #pragma unroll
  for (int i=0;i<8;i++){
    int m = m0 + ty*8 + i;
    float* row = xm + (size_t)m*DMODEL + col0;
    float4 p0 = make_float4(acc[i][0],acc[i][1],acc[i][2],acc[i][3]);
    float4 p1 = make_float4(acc[i][4],acc[i][5],acc[i][6],acc[i][7]);
    *(float4*)&row[0]=p0; *(float4*)&row[4]=p1;
  }
}

// ---------------- K8: LN2 stats over (x + xm) ----------------
__global__ void k8_ln2_stats(const float* __restrict__ x, const float* __restrict__ xm,
                             float* __restrict__ mu2, float* __restrict__ rs2){
  int blk = blockIdx.x;
  int b = blk / (LSEQ/32);
  int l0 = (blk % (LSEQ/32)) * 32;
  int t = threadIdx.x;
  int lc = t & 31, dc = t >> 5;
  const float* xb = x + (size_t)b*DMODEL*LSEQ;
  const float* xmr = xm + ((size_t)(b*LSEQ + l0 + lc))*DMODEL;
  float s=0.f, q=0.f;
  for (int d = dc*64; d < dc*64+64; ++d){
    float v = xb[(size_t)d*LSEQ + l0 + lc] + xmr[d];
    s += v; q += v*v;
  }
  __shared__ float ss[8][33], qq[8][33];
  ss[dc][lc]=s; qq[dc][lc]=q;
  __syncthreads();
  if (t < 32){
    float S=0.f,Q=0.f;
    for (int i=0;i<8;++i){S+=ss[i][t];Q+=qq[i][t];}
    float m = S/DMODEL;
    float var = Q/DMODEL - m*m;
    mu2[b*LSEQ+l0+t]=m;
    rs2[b*LSEQ+l0+t]=rsqrtf(var+1e-5f);
  }
}

// ---------------- K9: final LN apply + transpose to (B, DIM, L) ----------------
// grid: B*(DMODEL/64)*(LSEQ/64) = 512 blocks; 64x64 tile via LDS.
__global__ void k9_final(const float* __restrict__ x, const float* __restrict__ xm,
                         const float* __restrict__ mu2, const float* __restrict__ rs2,
                         const float* __restrict__ w2, const float* __restrict__ b2,
                         float* __restrict__ out){
  __shared__ float s[64][65];
  int blk = blockIdx.x;
  int lt = blk & 31; int dti = (blk>>5) & 7; int b = blk >> 8;
  int l0 = lt*64, d0 = dti*64;
  int t = threadIdx.x;
  for (int rr=0; rr<64; rr+=16){
    int r = rr + (t>>4);
    float4 v = *(const float4*)&xm[((size_t)(b*LSEQ + l0 + r))*DMODEL + d0 + (t&15)*4];
    int c = (t&15)*4;
    s[r][c+0]=v.x; s[r][c+1]=v.y; s[r][c+2]=v.z; s[r][c+3]=v.w;
  }
  __syncthreads();
  int lc = t & 63;
  int drb = (t>>6)*16;
  #pragma unroll
  for (int i=0;i<16;++i){
    int dr = drb + i;
    int dd = d0 + dr; int l = l0 + lc;
    float v = x[((size_t)(b*DMODEL + dd))*LSEQ + l] + s[lc][dr];
    float o = (v - mu2[b*LSEQ+l]) * rs2[b*LSEQ+l] * w2[dd] + b2[dd];
    out[((size_t)(b*DMODEL+dd))*LSEQ + l] = o;
  }
}

extern "C" void kernel_launch(void* const* d_in, const int* in_sizes, int n_in,
                              void* d_out, int out_size, void* d_ws, size_t ws_size,
                              hipStream_t stream) {
  const float* x      = (const float*)d_in[0];
  const float* n1w    = (const float*)d_in[1];
  const float* n1b    = (const float*)d_in[2];
  const float* n2w    = (const float*)d_in[3];
  const float* n2b    = (const float*)d_in[4];
  const float* Wip    = (const float*)d_in[5];
  const float* cw     = (const float*)d_in[6];
  const float* cb     = (const float*)d_in[7];
  const float* Wxp    = (const float*)d_in[8];
  const float* Wdt    = (const float*)d_in[9];
  const float* dtbias = (const float*)d_in[10];
  const float* Alog   = (const float*)d_in[11];
  const float* Dp     = (const float*)d_in[12];
  const float* Wop    = (const float*)d_in[13];
  float* out = (float*)d_out;

  // Workspace layout (floats). Total: 16384 + 3*4194304 + 262144 = 12,861,440 fl ≈ 49.1 MB.
  float* ws  = (float*)d_ws;
  float* mu1 = ws;
  float* rs1 = ws + 4096;
  float* mu2 = ws + 8192;
  float* rs2 = ws + 12288;
  float* xin = ws + 16384;               // (B,L,E); reused as yT (B,E,L) after conv
  float* zb  = xin + 4194304;            // (B,L,E); reused as xm (B,L,DIM) after scan
  float* xcb = zb + 4194304;             // (B,L,E)
  float* dbl = xcb + 4194304;            // (B,L,64)
  float* yT = xin;
  float* xm = zb;

  k1_ln_stats<<<dim3(BSZ*(LSEQ/32)), dim3(256), 0, stream>>>(x, mu1, rs1);
  k2_inproj  <<<dim3(16,32),          dim3(256), 0, stream>>>(x, mu1, rs1, n1w, n1b, Wip, xin, zb);
  k3_conv    <<<dim3(4096),           dim3(256), 0, stream>>>(xin, cw, cb, xcb);
  k4_xproj   <<<dim3(128),            dim3(256), 0, stream>>>(xcb, Wxp, dbl);
  k6_scan    <<<dim3(BSZ*(DINNER/16)),dim3(256), 0, stream>>>(dbl, xcb, zb, Wdt, dtbias, Alog, Dp, yT);
  k7_outproj <<<dim3(4,32),           dim3(256), 0, stream>>>(yT, Wop, xm);
  k8_ln2_stats<<<dim3(BSZ*(LSEQ/32)), dim3(256), 0, stream>>>(x, xm, mu2, rs2);
  k9_final   <<<dim3(512),            dim3(256), 0, stream>>>(x, xm, mu2, rs2, n2w, n2b, out);
}

// Round 2
// 491.982 us; speedup vs baseline: 1.7672x; 1.7672x over previous
//
#include <hip/hip_runtime.h>
#include <hip/hip_bf16.h>
#include <math.h>

#define BSZ 2
#define LSEQ 2048
#define DMODEL 512
#define DINNER 1024
#define NST 16
#define RDT 32
#define GDBL 64   // RDT + 2*NST
#define NCH 16    // chunks over L
#define CHL 128   // steps per chunk

__device__ __forceinline__ float siluf(float x){ return x / (1.f + __expf(-x)); }
__device__ __forceinline__ float softplusf(float x){
  return (x > 20.f) ? x : log1pf(__expf(x));
}

// 16-lane-row sum via DPP row_shr (VALU pipe, no LDS). Result valid in lane n==0 of each 16-lane row.
__device__ __forceinline__ float red16(float p){
  int t;
  t = __builtin_amdgcn_update_dpp(0, __float_as_int(p), 0x118, 0xf, 0xf, true); p += __int_as_float(t);
  t = __builtin_amdgcn_update_dpp(0, __float_as_int(p), 0x114, 0xf, 0xf, true); p += __int_as_float(t);
  t = __builtin_amdgcn_update_dpp(0, __float_as_int(p), 0x112, 0xf, 0xf, true); p += __int_as_float(t);
  t = __builtin_amdgcn_update_dpp(0, __float_as_int(p), 0x111, 0xf, 0xf, true); p += __int_as_float(t);
  return p;
}

// ---------------- K1: LN1 stats (mu, rstd per (b,l)) ----------------
__global__ void k1_ln_stats(const float* __restrict__ x, float* __restrict__ mu, float* __restrict__ rs){
  int blk = blockIdx.x;
  int b = blk / (LSEQ/32);
  int l0 = (blk % (LSEQ/32)) * 32;
  int t = threadIdx.x;
  int lc = t & 31, dc = t >> 5;
  const float* xb = x + (size_t)b*DMODEL*LSEQ;
  float s=0.f, q=0.f;
  for (int d = dc*64; d < dc*64+64; ++d){
    float v = xb[(size_t)d*LSEQ + l0 + lc];
    s += v; q += v*v;
  }
  __shared__ float ss[8][33], qq[8][33];
  ss[dc][lc]=s; qq[dc][lc]=q;
  __syncthreads();
  if (t < 32){
    float S=0.f,Q=0.f;
    for (int i=0;i<8;++i){S+=ss[i][t];Q+=qq[i][t];}
    float m = S/DMODEL;
    float var = Q/DMODEL - m*m;
    mu[b*LSEQ+l0+t]=m;
    rs[b*LSEQ+l0+t]=rsqrtf(var+1e-5f);
  }
}

// ---------------- K2: in_proj GEMM with fused LN1 on A ----------------
__global__ __launch_bounds__(256) void k2_inproj(
    const float* __restrict__ x, const float* __restrict__ mu, const float* __restrict__ rs,
    const float* __restrict__ w1, const float* __restrict__ b1, const float* __restrict__ W,
    float* __restrict__ xin, float* __restrict__ z){
  __shared__ float As[8][128];
  __shared__ float Bs[8][130];
  __shared__ float mus[128], rss[128];
  int t = threadIdx.x;
  int n0 = blockIdx.x * 128;
  int m0 = blockIdx.y * 128;
  int b  = m0 >> 11;
  int l0 = m0 & (LSEQ-1);
  if (t < 128){ mus[t]=mu[m0+t]; rss[t]=rs[m0+t]; }
  int tx = t & 15, ty = t >> 4;
  float acc[8][8];
  #pragma unroll
  for(int i=0;i<8;i++){
    #pragma unroll
    for(int j=0;j<8;j++) acc[i][j]=0.f;
  }
  int akk = t >> 5;         // 0..7 (k row)
  int ac4 = (t & 31) * 4;   // m col
  int bn  = t & 127;        // n
  int bk4 = (t >> 7) * 4;   // 0 or 4
  __syncthreads();
  for (int k0 = 0; k0 < DMODEL; k0 += 8){
    float4 v = *(const float4*)&x[((size_t)(b*DMODEL + k0 + akk))*LSEQ + l0 + ac4];
    float w1v = w1[k0+akk], b1v = b1[k0+akk];
    As[akk][ac4+0] = (v.x - mus[ac4+0])*rss[ac4+0]*w1v + b1v;
    As[akk][ac4+1] = (v.y - mus[ac4+1])*rss[ac4+1]*w1v + b1v;
    As[akk][ac4+2] = (v.z - mus[ac4+2])*rss[ac4+2]*w1v + b1v;
    As[akk][ac4+3] = (v.w - mus[ac4+3])*rss[ac4+3]*w1v + b1v;
    float4 wv = *(const float4*)&W[(size_t)(n0+bn)*DMODEL + k0 + bk4];
    Bs[bk4+0][bn]=wv.x; Bs[bk4+1][bn]=wv.y; Bs[bk4+2][bn]=wv.z; Bs[bk4+3][bn]=wv.w;
    __syncthreads();
    #pragma unroll
    for (int kk=0;kk<8;++kk){
      float a[8], bb[8];
      #pragma unroll
      for (int i=0;i<8;i++) a[i]=As[kk][ty*8+i];
      #pragma unroll
      for (int j=0;j<8;j++) bb[j]=Bs[kk][tx*8+j];
      #pragma unroll
      for (int i=0;i<8;i++){
        #pragma unroll
        for (int j=0;j<8;j++) acc[i][j] += a[i]*bb[j];
      }
    }
    __syncthreads();
  }
  bool half = (n0 >= DINNER);
  float* outp = half ? z : xin;
  int col0 = n0 - (half?DINNER:0) + tx*8;
  #pragma unroll
  for (int i=0;i<8;i++){
    int m = m0 + ty*8 + i;
    float* row = outp + (size_t)m*DINNER + col0;
    float4 p0 = make_float4(acc[i][0],acc[i][1],acc[i][2],acc[i][3]);
    float4 p1 = make_float4(acc[i][4],acc[i][5],acc[i][6],acc[i][7]);
    *(float4*)&row[0]=p0; *(float4*)&row[4]=p1;
  }
}

// ---------------- K3: causal depthwise conv (K=4) + SiLU ----------------
__global__ void k3_conv(const float* __restrict__ xin, const float* __restrict__ cw,
                        const float* __restrict__ cb, float* __restrict__ xc){
  int idx = blockIdx.x*blockDim.x + threadIdx.x;
  int e4 = (idx & (DINNER/4 - 1)) * 4;
  int m = idx >> 8;
  int b = m >> 11; int l = m & (LSEQ-1);
  float4 accb = *(const float4*)&cb[e4];
  float acc[4] = {accb.x, accb.y, accb.z, accb.w};
  #pragma unroll
  for (int k=0;k<4;++k){
    int li = l + k - 3;
    if (li >= 0){
      float4 v = *(const float4*)&xin[((size_t)(b*LSEQ+li))*DINNER + e4];
      acc[0] += v.x * cw[(e4+0)*4 + k];
      acc[1] += v.y * cw[(e4+1)*4 + k];
      acc[2] += v.z * cw[(e4+2)*4 + k];
      acc[3] += v.w * cw[(e4+3)*4 + k];
    }
  }
  float4 o;
  o.x = siluf(acc[0]); o.y = siluf(acc[1]); o.z = siluf(acc[2]); o.w = siluf(acc[3]);
  *(float4*)&xc[(size_t)m*DINNER + e4] = o;
}

// ---------------- K4: x_proj (dbl[m][g] = xc[m]·Wxp[g]) ----------------
__global__ void k4_xproj(const float* __restrict__ xc, const float* __restrict__ Wxp,
                         float* __restrict__ dblo){
  int idx = blockIdx.x*blockDim.x + threadIdx.x;
  int g = idx & 63; int m0 = (idx >> 6) * 8;
  const float* wr = Wxp + (size_t)g*DINNER;
  float s[8] = {0.f,0.f,0.f,0.f,0.f,0.f,0.f,0.f};
  for (int k=0;k<DINNER;k+=4){
    float4 w = *(const float4*)&wr[k];
    #pragma unroll
    for (int j=0;j<8;++j){
      float4 a = *(const float4*)&xc[(size_t)(m0+j)*DINNER + k];
      s[j] += a.x*w.x + a.y*w.y + a.z*w.z + a.w*w.w;
    }
  }
  #pragma unroll
  for (int j=0;j<8;++j) dblo[(size_t)(m0+j)*GDBL + g] = s[j];
}

// ---------------- K6a: chunk-local scan (dt_proj fused), h0 = 0 ----------------
// grid: B * 64 d-slices * NCH chunks = 2048 blocks, block 256 (16d x 16n).
// Emits: ypart (=C·h_local + xc*D, pre-gate) into yT layout (B,DINNER,L);
//        Scum (inclusive cumsum of dt within chunk) same layout;
//        per-chunk summaries hend / dchunk = exp(A*S_total).
__global__ __launch_bounds__(256) void k6a_scanlocal(
    const float* __restrict__ dblg, const float* __restrict__ xcg,
    const float* __restrict__ Wdt, const float* __restrict__ dtbias,
    const float* __restrict__ Alog, const float* __restrict__ Dp,
    float* __restrict__ ypart, float* __restrict__ Scum,
    float* __restrict__ hend, float* __restrict__ dchunk){
  int blk = blockIdx.x;
  int b = blk >> 10;
  int slice = (blk >> 4) & 63;
  int chunk = blk & 15;
  int d0 = slice * 16;
  int t = threadIdx.x;
  int dl = t >> 4, n = t & 15;
  int d = d0 + dl;
  float Adn = -__expf(Alog[d*NST + n]);
  float Dv = Dp[d];
  float h = 0.f;
  float S = 0.f;

  __shared__ float dbls[32][36];
  __shared__ float Wdts[16][33];
  __shared__ float biass[16];
  __shared__ float dts_t[16][36];
  __shared__ float xcs_t[16][36];
  __shared__ float Bts[16][36];
  __shared__ float Cts[16][36];
  __shared__ float ys[16][33];
  __shared__ float Ss_l[16][33];

  {
    int c = t & 31, rr = t >> 5;
    Wdts[rr][c]   = Wdt[(size_t)(d0+rr)*RDT + c];
    Wdts[rr+8][c] = Wdt[(size_t)(d0+rr+8)*RDT + c];
    if (t < 16) biass[t] = dtbias[d0+t];
  }

  for (int sub = 0; sub < CHL/32; ++sub){
    int l0 = chunk*CHL + sub*32;
    __syncthreads();
    { // stage
      int c4 = (t & 7) * 4;
      int rr = t >> 3;
      float4 v = *(const float4*)&dblg[(size_t)(b*LSEQ + l0 + rr)*GDBL + c4];
      *(float4*)&dbls[rr][c4] = v;
      int c = t & 15;
      int r1 = t >> 4, r2 = r1 + 16;
      size_t row1 = (size_t)(b*LSEQ + l0 + r1);
      size_t row2 = (size_t)(b*LSEQ + l0 + r2);
      xcs_t[c][r1] = xcg[row1*DINNER + d0 + c];
      xcs_t[c][r2] = xcg[row2*DINNER + d0 + c];
      Bts[c][r1]   = dblg[row1*GDBL + RDT + c];
      Bts[c][r2]   = dblg[row2*GDBL + RDT + c];
      Cts[c][r1]   = dblg[row1*GDBL + RDT + NST + c];
      Cts[c][r2]   = dblg[row2*GDBL + RDT + NST + c];
    }
    __syncthreads();
    { // fused dt_proj + softplus
      int c = t & 15;
      int r1 = t >> 4, r2 = r1 + 16;
      float s1 = biass[c], s2 = biass[c];
      #pragma unroll
      for (int rr=0; rr<RDT; ++rr){
        float w = Wdts[c][rr];
        s1 += dbls[r1][rr] * w;
        s2 += dbls[r2][rr] * w;
      }
      dts_t[c][r1] = softplusf(s1);
      dts_t[c][r2] = softplusf(s2);
    }
    __syncthreads();
    for (int r0=0; r0<32; r0+=4){
      float4 dt4 = *(const float4*)&dts_t[dl][r0];
      float4 xc4 = *(const float4*)&xcs_t[dl][r0];
      float4 B4  = *(const float4*)&Bts[n][r0];
      float4 C4  = *(const float4*)&Cts[n][r0];
      const float* dtp = (const float*)&dt4;
      const float* xcp = (const float*)&xc4;
      const float* Bp  = (const float*)&B4;
      const float* Cp  = (const float*)&C4;
      #pragma unroll
      for (int j=0;j<4;++j){
        int r = r0 + j;
        float dtv = dtp[j];
        float a = __expf(dtv * Adn);
        h = a*h + dtv * Bp[j] * xcp[j];
        S += dtv;
        float p = red16(h * Cp[j]);
        if (n == 0){
          ys[dl][r]   = p + xcp[j]*Dv;
          Ss_l[dl][r] = S;
        }
      }
    }
    __syncthreads();
    { // write ypart + Scum chunk, (B,DINNER,L) layout
      int c = t & 31;
      int rr = t >> 5;
      size_t o1 = ((size_t)(b*DINNER + d0 + rr))*LSEQ + l0 + c;
      size_t o2 = ((size_t)(b*DINNER + d0 + rr + 8))*LSEQ + l0 + c;
      ypart[o1] = ys[rr][c];     ypart[o2] = ys[rr+8][c];
      Scum[o1]  = Ss_l[rr][c];   Scum[o2]  = Ss_l[rr+8][c];
    }
  }
  // chunk summaries
  int cix = ((b*NCH + chunk)*DINNER + d)*NST + n;
  hend[cix]   = h;
  dchunk[cix] = __expf(Adn * S);
}

// ---------------- K6b: sequential combine over chunks (exclusive scan) ----------------
// grid: 128 blocks x 256 = 32768 threads = B*DINNER*NST.
__global__ void k6b_combine(const float* __restrict__ hend, const float* __restrict__ dchunk,
                            float* __restrict__ h0s){
  int idx = blockIdx.x*blockDim.x + threadIdx.x;
  int b = idx >> 14;
  int r = idx & 16383;
  float h = 0.f;
  #pragma unroll
  for (int c=0; c<NCH; ++c){
    int base = ((b*NCH + c) << 14) + r;
    h0s[base] = h;
    h = dchunk[base]*h + hend[base];
  }
}

// ---------------- K6c: correction + gate (fully parallel) ----------------
// y_t = (ypart_t + sum_n C_t[n]*exp(A[d,n]*S_t[d])*h0[d,n]) * silu(z_t[d]); in-place on ypart.
__global__ __launch_bounds__(256) void k6c_fixup(
    const float* __restrict__ dblg, const float* __restrict__ zg,
    const float* __restrict__ Alog, const float* __restrict__ Scum,
    const float* __restrict__ h0s, float* __restrict__ yT){
  int blk = blockIdx.x;
  int b = blk >> 10;
  int slice = (blk >> 4) & 63;
  int chunk = blk & 15;
  int d0 = slice * 16;
  int t = threadIdx.x;
  int dl = t >> 4, n = t & 15;
  int d = d0 + dl;
  float Adn = -__expf(Alog[d*NST + n]);
  float h0v = h0s[((size_t)(b*NCH + chunk) << 14) + (d<<4) + n];

  __shared__ float Cts[16][36];
  __shared__ float zs[32][17];
  __shared__ float Ss_s[16][36];
  __shared__ float ys_s[16][36];

  for (int sub = 0; sub < CHL/32; ++sub){
    int l0 = chunk*CHL + sub*32;
    __syncthreads();
    { // stage: Ss_s/ys_s via float4 (split threads), C_t and z per-element
      if (t < 128){
        int dr = t >> 3, c4 = (t & 7) * 4;
        *(float4*)&Ss_s[dr][c4] = *(const float4*)&Scum[((size_t)(b*DINNER + d0 + dr))*LSEQ + l0 + c4];
      } else {
        int t2 = t - 128;
        int dr = t2 >> 3, c4 = (t2 & 7) * 4;
        *(float4*)&ys_s[dr][c4] = *(const float4*)&yT[((size_t)(b*DINNER + d0 + dr))*LSEQ + l0 + c4];
      }
      int c = t & 15;
      int r1 = t >> 4, r2 = r1 + 16;
      size_t row1 = (size_t)(b*LSEQ + l0 + r1);
      size_t row2 = (size_t)(b*LSEQ + l0 + r2);
      Cts[c][r1] = dblg[row1*GDBL + RDT + NST + c];
      Cts[c][r2] = dblg[row2*GDBL + RDT + NST + c];
      zs[r1][c]  = zg[row1*DINNER + d0 + c];
      zs[r2][c]  = zg[row2*DINNER + d0 + c];
    }
    __syncthreads();
    for (int r0=0; r0<32; r0+=4){
      float4 S4 = *(const float4*)&Ss_s[dl][r0];
      float4 C4 = *(const float4*)&Cts[n][r0];
      const float* Sp = (const float*)&S4;
      const float* Cp = (const float*)&C4;
      #pragma unroll
      for (int j=0;j<4;++j){
        int r = r0 + j;
        float e = __expf(Adn * Sp[j]);
        float p = red16(Cp[j] * e * h0v);
        if (n == 0){
          float y = (ys_s[dl][r] + p) * siluf(zs[r][dl]);
          ys_s[dl][r] = y;
        }
      }
    }
    __syncthreads();
    { // write final y chunk
      int c = t & 31;
      int rr = t >> 5;
      yT[((size_t)(b*DINNER + d0 + rr))*LSEQ + l0 + c]     = ys_s[rr][c];
      yT[((size_t)(b*DINNER + d0 + rr + 8))*LSEQ + l0 + c] = ys_s[rr+8][c];
    }
  }
}

// ---------------- K7: out_proj GEMM (64x64 tiles, all CUs) ----------------
__global__ __launch_bounds__(256) void k7_outproj(
    const float* __restrict__ yT, const float* __restrict__ W, float* __restrict__ xm){
  __shared__ float As[8][64];
  __shared__ float Bs[8][66];
  int t = threadIdx.x;
  int n0 = blockIdx.x * 64;
  int m0 = blockIdx.y * 64;
  int b  = m0 >> 11;
  int l0 = m0 & (LSEQ-1);
  int tx = t & 15, ty = t >> 4;
  float acc[4][4];
  #pragma unroll
  for(int i=0;i<4;i++){
    #pragma unroll
    for(int j=0;j<4;j++) acc[i][j]=0.f;
  }
  int akk = t >> 5;         // 0..7
  int ac2 = (t & 31) * 2;   // 0..62
  int bn  = t & 63;
  int bk2 = (t >> 6) * 2;   // 0,2,4,6
  for (int k0 = 0; k0 < DINNER; k0 += 8){
    float2 v = *(const float2*)&yT[((size_t)(b*DINNER + k0 + akk))*LSEQ + l0 + ac2];
    As[akk][ac2]=v.x; As[akk][ac2+1]=v.y;
    float2 wv = *(const float2*)&W[(size_t)(n0+bn)*DINNER + k0 + bk2];
    Bs[bk2][bn]=wv.x; Bs[bk2+1][bn]=wv.y;
    __syncthreads();
    #pragma unroll
    for (int kk=0;kk<8;++kk){
      float a[4], bb[4];
      #pragma unroll
      for (int i=0;i<4;i++) a[i]=As[kk][ty*4+i];
      #pragma unroll
      for (int j=0;j<4;j++) bb[j]=Bs[kk][tx*4+j];
      #pragma unroll
      for (int i=0;i<4;i++){
        #pragma unroll
        for (int j=0;j<4;j++) acc[i][j] += a[i]*bb[j];
      }
    }
    __syncthreads();
  }
  int col0 = n0 + tx*4;
  #pragma unroll
  for (int i=0;i<4;i++){
    int m = m0 + ty*4 + i;
    float* row = xm + (size_t)m*DMODEL + col0;
    *(float4*)&row[0] = make_float4(acc[i][0],acc[i][1],acc[i][2],acc[i][3]);
  }
}

// ---------------- K8: LN2 stats over (x + xm) ----------------
__global__ void k8_ln2_stats(const float* __restrict__ x, const float* __restrict__ xm,
                             float* __restrict__ mu2, float* __restrict__ rs2){
  int blk = blockIdx.x;
  int b = blk / (LSEQ/32);
  int l0 = (blk % (LSEQ/32)) * 32;
  int t = threadIdx.x;
  int lc = t & 31, dc = t >> 5;
  const float* xb = x + (size_t)b*DMODEL*LSEQ;
  const float* xmr = xm + ((size_t)(b*LSEQ + l0 + lc))*DMODEL;
  float s=0.f, q=0.f;
  for (int d = dc*64; d < dc*64+64; ++d){
    float v = xb[(size_t)d*LSEQ + l0 + lc] + xmr[d];
    s += v; q += v*v;
  }
  __shared__ float ss[8][33], qq[8][33];
  ss[dc][lc]=s; qq[dc][lc]=q;
  __syncthreads();
  if (t < 32){
    float S=0.f,Q=0.f;
    for (int i=0;i<8;++i){S+=ss[i][t];Q+=qq[i][t];}
    float m = S/DMODEL;
    float var = Q/DMODEL - m*m;
    mu2[b*LSEQ+l0+t]=m;
    rs2[b*LSEQ+l0+t]=rsqrtf(var+1e-5f);
  }
}

// ---------------- K9: final LN apply + transpose to (B, DIM, L) ----------------
__global__ void k9_final(const float* __restrict__ x, const float* __restrict__ xm,
                         const float* __restrict__ mu2, const float* __restrict__ rs2,
                         const float* __restrict__ w2, const float* __restrict__ b2,
                         float* __restrict__ out){
  __shared__ float s[64][65];
  int blk = blockIdx.x;
  int lt = blk & 31; int dti = (blk>>5) & 7; int b = blk >> 8;
  int l0 = lt*64, d0 = dti*64;
  int t = threadIdx.x;
  for (int rr=0; rr<64; rr+=16){
    int r = rr + (t>>4);
    float4 v = *(const float4*)&xm[((size_t)(b*LSEQ + l0 + r))*DMODEL + d0 + (t&15)*4];
    int c = (t&15)*4;
    s[r][c+0]=v.x; s[r][c+1]=v.y; s[r][c+2]=v.z; s[r][c+3]=v.w;
  }
  __syncthreads();
  int lc = t & 63;
  int drb = (t>>6)*16;
  #pragma unroll
  for (int i=0;i<16;++i){
    int dr = drb + i;
    int dd = d0 + dr; int l = l0 + lc;
    float v = x[((size_t)(b*DMODEL + dd))*LSEQ + l] + s[lc][dr];
    float o = (v - mu2[b*LSEQ+l]) * rs2[b*LSEQ+l] * w2[dd] + b2[dd];
    out[((size_t)(b*DMODEL+dd))*LSEQ + l] = o;
  }
}

extern "C" void kernel_launch(void* const* d_in, const int* in_sizes, int n_in,
                              void* d_out, int out_size, void* d_ws, size_t ws_size,
                              hipStream_t stream) {
  const float* x      = (const float*)d_in[0];
  const float* n1w    = (const float*)d_in[1];
  const float* n1b    = (const float*)d_in[2];
  const float* n2w    = (const float*)d_in[3];
  const float* n2b    = (const float*)d_in[4];
  const float* Wip    = (const float*)d_in[5];
  const float* cw     = (const float*)d_in[6];
  const float* cb     = (const float*)d_in[7];
  const float* Wxp    = (const float*)d_in[8];
  const float* Wdt    = (const float*)d_in[9];
  const float* dtbias = (const float*)d_in[10];
  const float* Alog   = (const float*)d_in[11];
  const float* Dp     = (const float*)d_in[12];
  const float* Wop    = (const float*)d_in[13];
  float* out = (float*)d_out;

  // Workspace layout (floats):
  // 16384 (stats) + 3*4194304 (xin/zb/xcb) + 262144 (dbl) + 4194304 (Scum)
  // + 3*524288 (hend/dchunk/h0s) = 18,630,656 floats ≈ 74.5 MB.
  float* ws  = (float*)d_ws;
  float* mu1 = ws;
  float* rs1 = ws + 4096;
  float* mu2 = ws + 8192;
  float* rs2 = ws + 12288;
  float* xin = ws + 16384;               // (B,L,E); reused as ypart/yT (B,E,L) after conv
  float* zb  = xin + 4194304;            // (B,L,E); reused as xm (B,L,DIM) after scan
  float* xcb = zb + 4194304;             // (B,L,E)
  float* dbl = xcb + 4194304;            // (B,L,64)
  float* Scum = dbl + 262144;            // (B,E,L)
  float* hend = Scum + 4194304;          // (B,NCH,E,NST)
  float* dchk = hend + 524288;
  float* h0s  = dchk + 524288;
  float* yT = xin;
  float* xm = zb;

  k1_ln_stats<<<dim3(BSZ*(LSEQ/32)), dim3(256), 0, stream>>>(x, mu1, rs1);
  k2_inproj  <<<dim3(16,32),          dim3(256), 0, stream>>>(x, mu1, rs1, n1w, n1b, Wip, xin, zb);
  k3_conv    <<<dim3(4096),           dim3(256), 0, stream>>>(xin, cw, cb, xcb);
  k4_xproj   <<<dim3(128),            dim3(256), 0, stream>>>(xcb, Wxp, dbl);
  k6a_scanlocal<<<dim3(BSZ*64*NCH),   dim3(256), 0, stream>>>(dbl, xcb, Wdt, dtbias, Alog, Dp, yT, Scum, hend, dchk);
  k6b_combine<<<dim3(128),            dim3(256), 0, stream>>>(hend, dchk, h0s);
  k6c_fixup  <<<dim3(BSZ*64*NCH),     dim3(256), 0, stream>>>(dbl, zb, Alog, Scum, h0s, yT);
  k7_outproj <<<dim3(8,64),           dim3(256), 0, stream>>>(yT, Wop, xm);
  k8_ln2_stats<<<dim3(BSZ*(LSEQ/32)), dim3(256), 0, stream>>>(x, xm, mu2, rs2);
  k9_final   <<<dim3(512),            dim3(256), 0, stream>>>(x, xm, mu2, rs2, n2w, n2b, out);
}

// Round 3
// 282.246 us; speedup vs baseline: 3.0804x; 1.7431x over previous
//
#include <hip/hip_runtime.h>
#include <math.h>

#define BSZ 2
#define LSEQ 2048
#define DMODEL 512
#define DINNER 1024
#define NST 16
#define RDT 32
#define GDBL 64   // RDT + 2*NST
#define NCH 16    // chunks over L
#define CHL 128   // steps per chunk

typedef unsigned short u16;
typedef unsigned int   u32;
typedef __attribute__((ext_vector_type(8))) __bf16 bf16x8;
typedef __attribute__((ext_vector_type(4))) float  f32x4;

__device__ __forceinline__ float siluf(float x){ return x / (1.f + __expf(-x)); }
__device__ __forceinline__ float softplusf(float x){
  return (x > 20.f) ? x : log1pf(__expf(x));
}
__device__ __forceinline__ u16 f2bf(float f){
  u32 u = __float_as_uint(f);
  u += 0x7fff + ((u >> 16) & 1);
  return (u16)(u >> 16);
}
// async global->LDS, 16B per lane; lds dest must be wave-uniform base (lane*16 auto)
__device__ __forceinline__ void gld16(const void* g, void* l){
  __builtin_amdgcn_global_load_lds((const __attribute__((address_space(1))) void*)g,
                                   (__attribute__((address_space(3))) void*)l, 16, 0, 0);
}

// 16-lane-row sum via DPP row_shr. Result valid in lane n==0 of each 16-lane row.
__device__ __forceinline__ float red16(float p){
  int t;
  t = __builtin_amdgcn_update_dpp(0, __float_as_int(p), 0x118, 0xf, 0xf, true); p += __int_as_float(t);
  t = __builtin_amdgcn_update_dpp(0, __float_as_int(p), 0x114, 0xf, 0xf, true); p += __int_as_float(t);
  t = __builtin_amdgcn_update_dpp(0, __float_as_int(p), 0x112, 0xf, 0xf, true); p += __int_as_float(t);
  t = __builtin_amdgcn_update_dpp(0, __float_as_int(p), 0x111, 0xf, 0xf, true); p += __int_as_float(t);
  return p;
}

// ---------------- K0: weight conversion fp32 -> bf16 ----------------
__global__ void k0_wcvt(const float* __restrict__ Wip, const float* __restrict__ Wop,
                        u16* __restrict__ wipb, u16* __restrict__ wopb){
  int idx = blockIdx.x*256 + threadIdx.x;
  int i4 = idx * 4;
  const float* src; u16* dst;
  if (i4 < 2048*512){ src = Wip + i4; dst = wipb + i4; }
  else { int j = i4 - 2048*512; src = Wop + j; dst = wopb + j; }
  float4 v = *(const float4*)src;
  u32 lo = (u32)f2bf(v.x) | ((u32)f2bf(v.y) << 16);
  u32 hi = (u32)f2bf(v.z) | ((u32)f2bf(v.w) << 16);
  *(uint2*)dst = make_uint2(lo, hi);
}

// ---------------- K1: LN1 stats + normalize + transpose-write bf16 (B,L,D) ----------------
// grid: BSZ*64 = 128 blocks of 32 l each; block 256.
__global__ void k1_ln_norm(const float* __restrict__ x, const float* __restrict__ w1,
                           const float* __restrict__ b1, u16* __restrict__ xnb){
  int blk = blockIdx.x;
  int b = blk >> 6;
  int l0 = (blk & 63) * 32;
  int t = threadIdx.x;
  int lc = t & 31, dc = t >> 5;
  const float* xb = x + (size_t)b*DMODEL*LSEQ;
  float s=0.f, q=0.f;
  for (int d = dc*64; d < dc*64+64; ++d){
    float v = xb[d*LSEQ + l0 + lc];
    s += v; q += v*v;
  }
  __shared__ float ss[8][33], qq[8][33];
  __shared__ float muL[32], rsL[32];
  ss[dc][lc]=s; qq[dc][lc]=q;
  __syncthreads();
  if (t < 32){
    float S=0.f,Q=0.f;
    for (int i=0;i<8;++i){S+=ss[i][t];Q+=qq[i][t];}
    float m = S/DMODEL;
    muL[t]=m; rsL[t]=rsqrtf(Q/DMODEL - m*m + 1e-5f);
  }
  __syncthreads();
  float mu = muL[lc], rs = rsL[lc];
  u16* orow = xnb + ((size_t)(b*LSEQ + l0 + lc))*DMODEL;
  for (int d = dc*64; d < dc*64+64; d += 2){
    float v0 = (xb[d*LSEQ + l0 + lc]     - mu)*rs*w1[d]   + b1[d];
    float v1 = (xb[(d+1)*LSEQ + l0 + lc] - mu)*rs*w1[d+1] + b1[d+1];
    *(u32*)&orow[d] = (u32)f2bf(v0) | ((u32)f2bf(v1) << 16);
  }
}

// ---------------- K2: in_proj bf16 MFMA GEMM ----------------
// C[m][e] = sum_d xnb[m][d] * wipb[e][d]; M=4096, N=2048, K=512.
// 128x128 tile, BK=32, 4 waves (2x2), per-wave 64x64 = 4x4 frags of 16x16x32.
__global__ __launch_bounds__(256) void k2_inproj_mfma(
    const u16* __restrict__ xnb, const u16* __restrict__ wipb,
    float* __restrict__ xin, float* __restrict__ z){
  __shared__ u16 As[2][4096];
  __shared__ u16 Bs[2][4096];
  int t = threadIdx.x;
  int wid = t >> 6, lane = t & 63;
  int n0 = blockIdx.x * 128, m0 = blockIdx.y * 128;
  int wr = wid >> 1, wc = wid & 1;
  int lr = lane & 15, q = lane >> 4;

  const u16* gA = xnb  + (size_t)(m0 + (t>>2))*DMODEL + (t&3)*8;
  const u16* gB = wipb + (size_t)(n0 + (t>>2))*DMODEL + (t&3)*8;

  f32x4 acc[4][4];
  #pragma unroll
  for (int i=0;i<4;++i)
    #pragma unroll
    for (int j=0;j<4;++j) acc[i][j] = (f32x4){0.f,0.f,0.f,0.f};

  #pragma unroll
  for (int r=0;r<2;++r){
    gld16(gA + (size_t)r*64*DMODEL, &As[0][(wid*64 + r*256)*8]);
    gld16(gB + (size_t)r*64*DMODEL, &Bs[0][(wid*64 + r*256)*8]);
  }
  const int abase = (wr*64 + lr)*32 + q*8;
  const int bbase = (wc*64 + lr)*32 + q*8;

  for (int ks = 0; ks < 16; ++ks){
    int cur = ks & 1;
    __syncthreads();                 // drains vmcnt -> buf[cur] ready
    if (ks < 15){
      const u16* gA2 = gA + (ks+1)*32;
      const u16* gB2 = gB + (ks+1)*32;
      #pragma unroll
      for (int r=0;r<2;++r){
        gld16(gA2 + (size_t)r*64*DMODEL, &As[cur^1][(wid*64 + r*256)*8]);
        gld16(gB2 + (size_t)r*64*DMODEL, &Bs[cur^1][(wid*64 + r*256)*8]);
      }
    }
    bf16x8 a[4], bv[4];
    #pragma unroll
    for (int mf=0; mf<4; ++mf) a[mf]  = *(const bf16x8*)&As[cur][abase + mf*512];
    #pragma unroll
    for (int nf=0; nf<4; ++nf) bv[nf] = *(const bf16x8*)&Bs[cur][bbase + nf*512];
    #pragma unroll
    for (int mf=0; mf<4; ++mf)
      #pragma unroll
      for (int nf=0; nf<4; ++nf)
        acc[mf][nf] = __builtin_amdgcn_mfma_f32_16x16x32_bf16(a[mf], bv[nf], acc[mf][nf], 0, 0, 0);
  }

  bool half = (n0 >= DINNER);
  float* outp = half ? z : xin;
  int colb = (half ? n0 - DINNER : n0) + wc*64 + lr;
  #pragma unroll
  for (int mf=0; mf<4; ++mf){
    int rowb = m0 + wr*64 + mf*16 + q*4;
    #pragma unroll
    for (int nf=0; nf<4; ++nf){
      f32x4 v = acc[mf][nf];
      int col = colb + nf*16;
      #pragma unroll
      for (int j=0;j<4;++j) outp[(size_t)(rowb+j)*DINNER + col] = v[j];
    }
  }
}

// ---------------- K3: causal depthwise conv (K=4) + SiLU ----------------
__global__ void k3_conv(const float* __restrict__ xin, const float* __restrict__ cw,
                        const float* __restrict__ cb, float* __restrict__ xc){
  int idx = blockIdx.x*blockDim.x + threadIdx.x;
  int e4 = (idx & (DINNER/4 - 1)) * 4;
  int m = idx >> 8;
  int b = m >> 11; int l = m & (LSEQ-1);
  float4 accb = *(const float4*)&cb[e4];
  float acc[4] = {accb.x, accb.y, accb.z, accb.w};
  #pragma unroll
  for (int k=0;k<4;++k){
    int li = l + k - 3;
    if (li >= 0){
      float4 v = *(const float4*)&xin[((size_t)(b*LSEQ+li))*DINNER + e4];
      acc[0] += v.x * cw[(e4+0)*4 + k];
      acc[1] += v.y * cw[(e4+1)*4 + k];
      acc[2] += v.z * cw[(e4+2)*4 + k];
      acc[3] += v.w * cw[(e4+3)*4 + k];
    }
  }
  float4 o;
  o.x = siluf(acc[0]); o.y = siluf(acc[1]); o.z = siluf(acc[2]); o.w = siluf(acc[3]);
  *(float4*)&xc[(size_t)m*DINNER + e4] = o;
}

// ---------------- K4: x_proj (dbl[m][g] = xc[m]·Wxp[g]) ----------------
// GROUP=4 rows per thread; grid 256 blocks.
__global__ void k4_xproj(const float* __restrict__ xc, const float* __restrict__ Wxp,
                         float* __restrict__ dblo){
  int idx = blockIdx.x*256 + threadIdx.x;
  int g = idx & 63; int m0 = (idx >> 6) * 4;
  const float* wr = Wxp + (size_t)g*DINNER;
  float s[4] = {0.f,0.f,0.f,0.f};
  for (int k=0;k<DINNER;k+=4){
    float4 w = *(const float4*)&wr[k];
    #pragma unroll
    for (int j=0;j<4;++j){
      float4 a = *(const float4*)&xc[(size_t)(m0+j)*DINNER + k];
      s[j] += a.x*w.x + a.y*w.y + a.z*w.z + a.w*w.w;
    }
  }
  #pragma unroll
  for (int j=0;j<4;++j) dblo[(size_t)(m0+j)*GDBL + g] = s[j];
}

// ---------------- K6a: chunk-local scan (dt_proj fused), h0 = 0 ----------------
__global__ __launch_bounds__(256) void k6a_scanlocal(
    const float* __restrict__ dblg, const float* __restrict__ xcg,
    const float* __restrict__ Wdt, const float* __restrict__ dtbias,
    const float* __restrict__ Alog, const float* __restrict__ Dp,
    float* __restrict__ ypart, float* __restrict__ Scum,
    float* __restrict__ hend, float* __restrict__ dchunk){
  int blk = blockIdx.x;
  int b = blk >> 10;
  int slice = (blk >> 4) & 63;
  int chunk = blk & 15;
  int d0 = slice * 16;
  int t = threadIdx.x;
  int dl = t >> 4, n = t & 15;
  int d = d0 + dl;
  float Adn = -__expf(Alog[d*NST + n]);
  float Dv = Dp[d];
  float h = 0.f;
  float S = 0.f;

  __shared__ float dbls[32][36];
  __shared__ float Wdts[16][33];
  __shared__ float biass[16];
  __shared__ float dts_t[16][36];
  __shared__ float xcs_t[16][36];
  __shared__ float Bts[16][36];
  __shared__ float Cts[16][36];
  __shared__ float ys[16][33];
  __shared__ float Ss_l[16][33];

  {
    int c = t & 31, rr = t >> 5;
    Wdts[rr][c]   = Wdt[(size_t)(d0+rr)*RDT + c];
    Wdts[rr+8][c] = Wdt[(size_t)(d0+rr+8)*RDT + c];
    if (t < 16) biass[t] = dtbias[d0+t];
  }

  for (int sub = 0; sub < CHL/32; ++sub){
    int l0 = chunk*CHL + sub*32;
    __syncthreads();
    {
      int c4 = (t & 7) * 4;
      int rr = t >> 3;
      float4 v = *(const float4*)&dblg[(size_t)(b*LSEQ + l0 + rr)*GDBL + c4];
      *(float4*)&dbls[rr][c4] = v;
      int c = t & 15;
      int r1 = t >> 4, r2 = r1 + 16;
      size_t row1 = (size_t)(b*LSEQ + l0 + r1);
      size_t row2 = (size_t)(b*LSEQ + l0 + r2);
      xcs_t[c][r1] = xcg[row1*DINNER + d0 + c];
      xcs_t[c][r2] = xcg[row2*DINNER + d0 + c];
      Bts[c][r1]   = dblg[row1*GDBL + RDT + c];
      Bts[c][r2]   = dblg[row2*GDBL + RDT + c];
      Cts[c][r1]   = dblg[row1*GDBL + RDT + NST + c];
      Cts[c][r2]   = dblg[row2*GDBL + RDT + NST + c];
    }
    __syncthreads();
    {
      int c = t & 15;
      int r1 = t >> 4, r2 = r1 + 16;
      float s1 = biass[c], s2 = biass[c];
      #pragma unroll
      for (int rr=0; rr<RDT; ++rr){
        float w = Wdts[c][rr];
        s1 += dbls[r1][rr] * w;
        s2 += dbls[r2][rr] * w;
      }
      dts_t[c][r1] = softplusf(s1);
      dts_t[c][r2] = softplusf(s2);
    }
    __syncthreads();
    for (int r0=0; r0<32; r0+=4){
      float4 dt4 = *(const float4*)&dts_t[dl][r0];
      float4 xc4 = *(const float4*)&xcs_t[dl][r0];
      float4 B4  = *(const float4*)&Bts[n][r0];
      float4 C4  = *(const float4*)&Cts[n][r0];
      const float* dtp = (const float*)&dt4;
      const float* xcp = (const float*)&xc4;
      const float* Bp  = (const float*)&B4;
      const float* Cp  = (const float*)&C4;
      #pragma unroll
      for (int j=0;j<4;++j){
        int r = r0 + j;
        float dtv = dtp[j];
        float a = __expf(dtv * Adn);
        h = a*h + dtv * Bp[j] * xcp[j];
        S += dtv;
        float p = red16(h * Cp[j]);
        if (n == 0){
          ys[dl][r]   = p + xcp[j]*Dv;
          Ss_l[dl][r] = S;
        }
      }
    }
    __syncthreads();
    {
      int c = t & 31;
      int rr = t >> 5;
      size_t o1 = ((size_t)(b*DINNER + d0 + rr))*LSEQ + l0 + c;
      size_t o2 = ((size_t)(b*DINNER + d0 + rr + 8))*LSEQ + l0 + c;
      ypart[o1] = ys[rr][c];     ypart[o2] = ys[rr+8][c];
      Scum[o1]  = Ss_l[rr][c];   Scum[o2]  = Ss_l[rr+8][c];
    }
  }
  int cix = ((b*NCH + chunk)*DINNER + d)*NST + n;
  hend[cix]   = h;
  dchunk[cix] = __expf(Adn * S);
}

// ---------------- K6b: sequential combine over chunks ----------------
__global__ void k6b_combine(const float* __restrict__ hend, const float* __restrict__ dchunk,
                            float* __restrict__ h0s){
  int idx = blockIdx.x*blockDim.x + threadIdx.x;
  int b = idx >> 14;
  int r = idx & 16383;
  float h = 0.f;
  #pragma unroll
  for (int c=0; c<NCH; ++c){
    int base = ((b*NCH + c) << 14) + r;
    h0s[base] = h;
    h = dchunk[base]*h + hend[base];
  }
}

// ---------------- K6c: correction + gate, writes bf16 y (B,L,E) ----------------
__global__ __launch_bounds__(256) void k6c_fixup(
    const float* __restrict__ dblg, const float* __restrict__ zg,
    const float* __restrict__ Alog, const float* __restrict__ Scum,
    const float* __restrict__ h0s, const float* __restrict__ ypart,
    u16* __restrict__ ybf){
  int blk = blockIdx.x;
  int b = blk >> 10;
  int slice = (blk >> 4) & 63;
  int chunk = blk & 15;
  int d0 = slice * 16;
  int t = threadIdx.x;
  int dl = t >> 4, n = t & 15;
  int d = d0 + dl;
  float Adn = -__expf(Alog[d*NST + n]);
  float h0v = h0s[((size_t)(b*NCH + chunk) << 14) + (d<<4) + n];

  __shared__ float Cts[16][36];
  __shared__ float zs[32][17];
  __shared__ float Ss_s[16][36];
  __shared__ float ys_s[16][36];

  for (int sub = 0; sub < CHL/32; ++sub){
    int l0 = chunk*CHL + sub*32;
    __syncthreads();
    {
      if (t < 128){
        int dr = t >> 3, c4 = (t & 7) * 4;
        *(float4*)&Ss_s[dr][c4] = *(const float4*)&Scum[((size_t)(b*DINNER + d0 + dr))*LSEQ + l0 + c4];
      } else {
        int t2 = t - 128;
        int dr = t2 >> 3, c4 = (t2 & 7) * 4;
        *(float4*)&ys_s[dr][c4] = *(const float4*)&ypart[((size_t)(b*DINNER + d0 + dr))*LSEQ + l0 + c4];
      }
      int c = t & 15;
      int r1 = t >> 4, r2 = r1 + 16;
      size_t row1 = (size_t)(b*LSEQ + l0 + r1);
      size_t row2 = (size_t)(b*LSEQ + l0 + r2);
      Cts[c][r1] = dblg[row1*GDBL + RDT + NST + c];
      Cts[c][r2] = dblg[row2*GDBL + RDT + NST + c];
      zs[r1][c]  = zg[row1*DINNER + d0 + c];
      zs[r2][c]  = zg[row2*DINNER + d0 + c];
    }
    __syncthreads();
    for (int r0=0; r0<32; r0+=4){
      float4 S4 = *(const float4*)&Ss_s[dl][r0];
      float4 C4 = *(const float4*)&Cts[n][r0];
      const float* Sp = (const float*)&S4;
      const float* Cp = (const float*)&C4;
      #pragma unroll
      for (int j=0;j<4;++j){
        int r = r0 + j;
        float e = __expf(Adn * Sp[j]);
        float p = red16(Cp[j] * e * h0v);
        if (n == 0){
          ys_s[dl][r] = (ys_s[dl][r] + p) * siluf(zs[r][dl]);
        }
      }
    }
    __syncthreads();
    { // write bf16 y chunk, (B,L,E) layout: 2 bf16 per thread
      int r = t >> 3, pr = t & 7;
      float v0 = ys_s[pr*2][r];
      float v1 = ys_s[pr*2+1][r];
      u32 u = (u32)f2bf(v0) | ((u32)f2bf(v1) << 16);
      *(u32*)&ybf[((size_t)(b*LSEQ + l0 + r))*DINNER + d0 + pr*2] = u;
    }
  }
}

// ---------------- K7: out_proj bf16 MFMA GEMM ----------------
// xm[m][o] = sum_e ybf[m][e] * wopb[o][e]; M=4096, N=512, K=1024.
// 64x64 tile, BK=64 split as [s][64][32] in LDS; 4 waves (2x2), per-wave 32x32.
__global__ __launch_bounds__(256) void k7_outproj_mfma(
    const u16* __restrict__ ybf, const u16* __restrict__ wopb, float* __restrict__ xm){
  __shared__ u16 As[2][4096];
  __shared__ u16 Bs[2][4096];
  int t = threadIdx.x;
  int wid = t >> 6, lane = t & 63;
  int n0 = blockIdx.x * 64, m0 = blockIdx.y * 64;
  int wr = wid >> 1, wc = wid & 1;
  int lr = lane & 15, q = lane >> 4;

  const u16* gA = ybf  + (size_t)(m0 + (t>>2))*DINNER + (t&3)*8;
  const u16* gB = wopb + (size_t)(n0 + (t>>2))*DINNER + (t&3)*8;

  f32x4 acc[2][2];
  #pragma unroll
  for (int i=0;i<2;++i)
    #pragma unroll
    for (int j=0;j<2;++j) acc[i][j] = (f32x4){0.f,0.f,0.f,0.f};

  #pragma unroll
  for (int r=0;r<2;++r){  // round r stages k-slice r (32 k) of all 64 rows
    gld16(gA + r*32, &As[0][(r*256 + wid*64)*8]);
    gld16(gB + r*32, &Bs[0][(r*256 + wid*64)*8]);
  }
  const int abase = (wr*32 + lr)*32 + q*8;
  const int bbase = (wc*32 + lr)*32 + q*8;

  for (int ks = 0; ks < 16; ++ks){
    int cur = ks & 1;
    __syncthreads();
    if (ks < 15){
      const u16* gA2 = gA + (ks+1)*64;
      const u16* gB2 = gB + (ks+1)*64;
      #pragma unroll
      for (int r=0;r<2;++r){
        gld16(gA2 + r*32, &As[cur^1][(r*256 + wid*64)*8]);
        gld16(gB2 + r*32, &Bs[cur^1][(r*256 + wid*64)*8]);
      }
    }
    bf16x8 a[2][2], bv[2][2];
    #pragma unroll
    for (int mf=0; mf<2; ++mf)
      #pragma unroll
      for (int s=0; s<2; ++s) a[mf][s] = *(const bf16x8*)&As[cur][abase + mf*512 + s*2048];
    #pragma unroll
    for (int nf=0; nf<2; ++nf)
      #pragma unroll
      for (int s=0; s<2; ++s) bv[nf][s] = *(const bf16x8*)&Bs[cur][bbase + nf*512 + s*2048];
    #pragma unroll
    for (int s=0; s<2; ++s)
      #pragma unroll
      for (int mf=0; mf<2; ++mf)
        #pragma unroll
        for (int nf=0; nf<2; ++nf)
          acc[mf][nf] = __builtin_amdgcn_mfma_f32_16x16x32_bf16(a[mf][s], bv[nf][s], acc[mf][nf], 0, 0, 0);
  }

  #pragma unroll
  for (int mf=0; mf<2; ++mf){
    int rowb = m0 + wr*32 + mf*16 + q*4;
    #pragma unroll
    for (int nf=0; nf<2; ++nf){
      f32x4 v = acc[mf][nf];
      int col = n0 + wc*32 + nf*16 + lr;
      #pragma unroll
      for (int j=0;j<4;++j) xm[(size_t)(rowb+j)*DMODEL + col] = v[j];
    }
  }
}

// ---------------- K8: LN2 stats over (x + xm) ----------------
__global__ void k8_ln2_stats(const float* __restrict__ x, const float* __restrict__ xm,
                             float* __restrict__ mu2, float* __restrict__ rs2){
  int blk = blockIdx.x;
  int b = blk / (LSEQ/32);
  int l0 = (blk % (LSEQ/32)) * 32;
  int t = threadIdx.x;
  int lc = t & 31, dc = t >> 5;
  const float* xb = x + (size_t)b*DMODEL*LSEQ;
  const float* xmr = xm + ((size_t)(b*LSEQ + l0 + lc))*DMODEL;
  float s=0.f, q=0.f;
  for (int d = dc*64; d < dc*64+64; ++d){
    float v = xb[(size_t)d*LSEQ + l0 + lc] + xmr[d];
    s += v; q += v*v;
  }
  __shared__ float ss[8][33], qq[8][33];
  ss[dc][lc]=s; qq[dc][lc]=q;
  __syncthreads();
  if (t < 32){
    float S=0.f,Q=0.f;
    for (int i=0;i<8;++i){S+=ss[i][t];Q+=qq[i][t];}
    float m = S/DMODEL;
    float var = Q/DMODEL - m*m;
    mu2[b*LSEQ+l0+t]=m;
    rs2[b*LSEQ+l0+t]=rsqrtf(var+1e-5f);
  }
}

// ---------------- K9: final LN apply + transpose to (B, DIM, L) ----------------
__global__ void k9_final(const float* __restrict__ x, const float* __restrict__ xm,
                         const float* __restrict__ mu2, const float* __restrict__ rs2,
                         const float* __restrict__ w2, const float* __restrict__ b2,
                         float* __restrict__ out){
  __shared__ float s[64][65];
  int blk = blockIdx.x;
  int lt = blk & 31; int dti = (blk>>5) & 7; int b = blk >> 8;
  int l0 = lt*64, d0 = dti*64;
  int t = threadIdx.x;
  for (int rr=0; rr<64; rr+=16){
    int r = rr + (t>>4);
    float4 v = *(const float4*)&xm[((size_t)(b*LSEQ + l0 + r))*DMODEL + d0 + (t&15)*4];
    int c = (t&15)*4;
    s[r][c+0]=v.x; s[r][c+1]=v.y; s[r][c+2]=v.z; s[r][c+3]=v.w;
  }
  __syncthreads();
  int lc = t & 63;
  int drb = (t>>6)*16;
  #pragma unroll
  for (int i=0;i<16;++i){
    int dr = drb + i;
    int dd = d0 + dr; int l = l0 + lc;
    float v = x[((size_t)(b*DMODEL + dd))*LSEQ + l] + s[lc][dr];
    float o = (v - mu2[b*LSEQ+l]) * rs2[b*LSEQ+l] * w2[dd] + b2[dd];
    out[((size_t)(b*DMODEL+dd))*LSEQ + l] = o;
  }
}

extern "C" void kernel_launch(void* const* d_in, const int* in_sizes, int n_in,
                              void* d_out, int out_size, void* d_ws, size_t ws_size,
                              hipStream_t stream) {
  const float* x      = (const float*)d_in[0];
  const float* n1w    = (const float*)d_in[1];
  const float* n1b    = (const float*)d_in[2];
  const float* n2w    = (const float*)d_in[3];
  const float* n2b    = (const float*)d_in[4];
  const float* Wip    = (const float*)d_in[5];
  const float* cw     = (const float*)d_in[6];
  const float* cb     = (const float*)d_in[7];
  const float* Wxp    = (const float*)d_in[8];
  const float* Wdt    = (const float*)d_in[9];
  const float* dtbias = (const float*)d_in[10];
  const float* Alog   = (const float*)d_in[11];
  const float* Dp     = (const float*)d_in[12];
  const float* Wop    = (const float*)d_in[13];
  float* out = (float*)d_out;

  // Workspace layout (floats), ~75.6 MB total:
  float* ws   = (float*)d_ws;
  float* mu2  = ws;                      // 4096
  float* rs2  = ws + 4096;               // 4096
  float* xin  = ws + 16384;              // (B,L,E) fp32; later ypart (B,E,L)
  float* zb   = xin + 4194304;           // (B,L,E) fp32; later xm (B,L,DIM)
  float* reg3 = zb + 4194304;            // 16MB region: xnb bf16 -> xcb fp32 -> ybf bf16
  float* dbl  = reg3 + 4194304;          // (B,L,64)
  float* Scum = dbl + 262144;            // (B,E,L) fp32; earlier wipb bf16
  float* hend = Scum + 4194304;          // (B,NCH,E,NST)
  float* dchk = hend + 524288;
  float* h0s  = dchk + 524288;
  u16*  wopb  = (u16*)(h0s + 524288);    // 512*1024 bf16

  u16*  xnb  = (u16*)reg3;               // (B,L,D) bf16  (dead after k2)
  float* xcb = reg3;                     // (B,L,E) fp32  (k3..k6a)
  u16*  ybf  = (u16*)reg3;               // (B,L,E) bf16  (k6c..k7, aliases dead xcb)
  u16*  wipb = (u16*)Scum;               // (2048,512) bf16 (dead before k6a writes Scum)
  float* ypart = xin;
  float* xm    = zb;

  k0_wcvt      <<<dim3(1536),        dim3(256), 0, stream>>>(Wip, Wop, wipb, wopb);
  k1_ln_norm   <<<dim3(BSZ*64),      dim3(256), 0, stream>>>(x, n1w, n1b, xnb);
  k2_inproj_mfma<<<dim3(16,32),      dim3(256), 0, stream>>>(xnb, wipb, xin, zb);
  k3_conv      <<<dim3(4096),        dim3(256), 0, stream>>>(xin, cw, cb, xcb);
  k4_xproj     <<<dim3(256),         dim3(256), 0, stream>>>(xcb, Wxp, dbl);
  k6a_scanlocal<<<dim3(BSZ*64*NCH),  dim3(256), 0, stream>>>(dbl, xcb, Wdt, dtbias, Alog, Dp, ypart, Scum, hend, dchk);
  k6b_combine  <<<dim3(128),         dim3(256), 0, stream>>>(hend, dchk, h0s);
  k6c_fixup    <<<dim3(BSZ*64*NCH),  dim3(256), 0, stream>>>(dbl, zb, Alog, Scum, h0s, ypart, ybf);
  k7_outproj_mfma<<<dim3(8,64),      dim3(256), 0, stream>>>(ybf, wopb, xm);
  k8_ln2_stats <<<dim3(BSZ*(LSEQ/32)), dim3(256), 0, stream>>>(x, xm, mu2, rs2);
  k9_final     <<<dim3(512),         dim3(256), 0, stream>>>(x, xm, mu2, rs2, n2w, n2b, out);
}

// Round 4
// 218.875 us; speedup vs baseline: 3.9722x; 1.2895x over previous
//
#include <hip/hip_runtime.h>
#include <math.h>

#define BSZ 2
#define LSEQ 2048
#define DMODEL 512
#define DINNER 1024
#define NST 16
#define RDT 32
#define GDBL 64   // RDT + 2*NST
#define NCH 16    // chunks over L
#define CHL 128   // steps per chunk

typedef unsigned short u16;
typedef unsigned int   u32;
typedef __attribute__((ext_vector_type(8))) __bf16 bf16x8;
typedef __attribute__((ext_vector_type(4))) float  f32x4;

__device__ __forceinline__ float siluf(float x){ return x / (1.f + __expf(-x)); }
__device__ __forceinline__ float softplusf(float x){
  return (x > 20.f) ? x : log1pf(__expf(x));
}
__device__ __forceinline__ u16 f2bf(float f){
  u32 u = __float_as_uint(f);
  u += 0x7fff + ((u >> 16) & 1);
  return (u16)(u >> 16);
}
__device__ __forceinline__ float bf2f(u16 u){ return __uint_as_float((u32)u << 16); }
// async global->LDS, 16B per lane; lds dest must be wave-uniform base (lane*16 auto)
__device__ __forceinline__ void gld16(const void* g, void* l){
  __builtin_amdgcn_global_load_lds((const __attribute__((address_space(1))) void*)g,
                                   (__attribute__((address_space(3))) void*)l, 16, 0, 0);
}

// 16-lane-row sum via DPP row_shr. Result valid in lane n==0 of each 16-lane row.
__device__ __forceinline__ float red16(float p){
  int t;
  t = __builtin_amdgcn_update_dpp(0, __float_as_int(p), 0x118, 0xf, 0xf, true); p += __int_as_float(t);
  t = __builtin_amdgcn_update_dpp(0, __float_as_int(p), 0x114, 0xf, 0xf, true); p += __int_as_float(t);
  t = __builtin_amdgcn_update_dpp(0, __float_as_int(p), 0x112, 0xf, 0xf, true); p += __int_as_float(t);
  t = __builtin_amdgcn_update_dpp(0, __float_as_int(p), 0x111, 0xf, 0xf, true); p += __int_as_float(t);
  return p;
}

// ---------------- K0: weight conversion fp32 -> bf16 (Wip, Wop, Wxp) ----------------
__global__ void k0_wcvt(const float* __restrict__ Wip, const float* __restrict__ Wop,
                        const float* __restrict__ Wxp,
                        u16* __restrict__ wipb, u16* __restrict__ wopb, u16* __restrict__ wxpb){
  int idx = blockIdx.x*256 + threadIdx.x;
  int i4 = idx * 4;
  const float* src; u16* dst;
  if (i4 < 1048576){ src = Wip + i4; dst = wipb + i4; }
  else if (i4 < 1048576 + 524288){ int j = i4 - 1048576; src = Wop + j; dst = wopb + j; }
  else { int j = i4 - 1048576 - 524288; src = Wxp + j; dst = wxpb + j; }
  float4 v = *(const float4*)src;
  u32 lo = (u32)f2bf(v.x) | ((u32)f2bf(v.y) << 16);
  u32 hi = (u32)f2bf(v.z) | ((u32)f2bf(v.w) << 16);
  *(uint2*)dst = make_uint2(lo, hi);
}

// ---------------- K1: LN1 stats + normalize + transpose-write bf16 (B,L,D) ----------------
__global__ void k1_ln_norm(const float* __restrict__ x, const float* __restrict__ w1,
                           const float* __restrict__ b1, u16* __restrict__ xnb){
  int blk = blockIdx.x;
  int b = blk >> 6;
  int l0 = (blk & 63) * 32;
  int t = threadIdx.x;
  int lc = t & 31, dc = t >> 5;
  const float* xb = x + (size_t)b*DMODEL*LSEQ;
  float s=0.f, q=0.f;
  for (int d = dc*64; d < dc*64+64; ++d){
    float v = xb[d*LSEQ + l0 + lc];
    s += v; q += v*v;
  }
  __shared__ float ss[8][33], qq[8][33];
  __shared__ float muL[32], rsL[32];
  ss[dc][lc]=s; qq[dc][lc]=q;
  __syncthreads();
  if (t < 32){
    float S=0.f,Q=0.f;
    for (int i=0;i<8;++i){S+=ss[i][t];Q+=qq[i][t];}
    float m = S/DMODEL;
    muL[t]=m; rsL[t]=rsqrtf(Q/DMODEL - m*m + 1e-5f);
  }
  __syncthreads();
  float mu = muL[lc], rs = rsL[lc];
  u16* orow = xnb + ((size_t)(b*LSEQ + l0 + lc))*DMODEL;
  for (int d = dc*64; d < dc*64+64; d += 2){
    float v0 = (xb[d*LSEQ + l0 + lc]     - mu)*rs*w1[d]   + b1[d];
    float v1 = (xb[(d+1)*LSEQ + l0 + lc] - mu)*rs*w1[d+1] + b1[d+1];
    *(u32*)&orow[d] = (u32)f2bf(v0) | ((u32)f2bf(v1) << 16);
  }
}

// ---------------- K2: in_proj bf16 MFMA GEMM ----------------
// C[m][e] = sum_d xnb[m][d] * wipb[e][d]; M=4096, N=2048, K=512.
__global__ __launch_bounds__(256) void k2_inproj_mfma(
    const u16* __restrict__ xnb, const u16* __restrict__ wipb,
    float* __restrict__ xin, float* __restrict__ z){
  __shared__ u16 As[2][4096];
  __shared__ u16 Bs[2][4096];
  int t = threadIdx.x;
  int wid = t >> 6, lane = t & 63;
  int n0 = blockIdx.x * 128, m0 = blockIdx.y * 128;
  int wr = wid >> 1, wc = wid & 1;
  int lr = lane & 15, q = lane >> 4;

  const u16* gA = xnb  + (size_t)(m0 + (t>>2))*DMODEL + (t&3)*8;
  const u16* gB = wipb + (size_t)(n0 + (t>>2))*DMODEL + (t&3)*8;

  f32x4 acc[4][4];
  #pragma unroll
  for (int i=0;i<4;++i)
    #pragma unroll
    for (int j=0;j<4;++j) acc[i][j] = (f32x4){0.f,0.f,0.f,0.f};

  #pragma unroll
  for (int r=0;r<2;++r){
    gld16(gA + (size_t)r*64*DMODEL, &As[0][(wid*64 + r*256)*8]);
    gld16(gB + (size_t)r*64*DMODEL, &Bs[0][(wid*64 + r*256)*8]);
  }
  const int abase = (wr*64 + lr)*32 + q*8;
  const int bbase = (wc*64 + lr)*32 + q*8;

  for (int ks = 0; ks < 16; ++ks){
    int cur = ks & 1;
    __syncthreads();
    if (ks < 15){
      const u16* gA2 = gA + (ks+1)*32;
      const u16* gB2 = gB + (ks+1)*32;
      #pragma unroll
      for (int r=0;r<2;++r){
        gld16(gA2 + (size_t)r*64*DMODEL, &As[cur^1][(wid*64 + r*256)*8]);
        gld16(gB2 + (size_t)r*64*DMODEL, &Bs[cur^1][(wid*64 + r*256)*8]);
      }
    }
    bf16x8 a[4], bv[4];
    #pragma unroll
    for (int mf=0; mf<4; ++mf) a[mf]  = *(const bf16x8*)&As[cur][abase + mf*512];
    #pragma unroll
    for (int nf=0; nf<4; ++nf) bv[nf] = *(const bf16x8*)&Bs[cur][bbase + nf*512];
    #pragma unroll
    for (int mf=0; mf<4; ++mf)
      #pragma unroll
      for (int nf=0; nf<4; ++nf)
        acc[mf][nf] = __builtin_amdgcn_mfma_f32_16x16x32_bf16(a[mf], bv[nf], acc[mf][nf], 0, 0, 0);
  }

  bool half = (n0 >= DINNER);
  float* outp = half ? z : xin;
  int colb = (half ? n0 - DINNER : n0) + wc*64 + lr;
  #pragma unroll
  for (int mf=0; mf<4; ++mf){
    int rowb = m0 + wr*64 + mf*16 + q*4;
    #pragma unroll
    for (int nf=0; nf<4; ++nf){
      f32x4 v = acc[mf][nf];
      int col = colb + nf*16;
      #pragma unroll
      for (int j=0;j<4;++j) outp[(size_t)(rowb+j)*DINNER + col] = v[j];
    }
  }
}

// ---------------- K3: causal depthwise conv (K=4) + SiLU -> bf16 xc ----------------
__global__ void k3_conv(const float* __restrict__ xin, const float* __restrict__ cw,
                        const float* __restrict__ cb, u16* __restrict__ xc){
  int idx = blockIdx.x*blockDim.x + threadIdx.x;
  int e4 = (idx & (DINNER/4 - 1)) * 4;
  int m = idx >> 8;
  int b = m >> 11; int l = m & (LSEQ-1);
  float4 accb = *(const float4*)&cb[e4];
  float acc[4] = {accb.x, accb.y, accb.z, accb.w};
  #pragma unroll
  for (int k=0;k<4;++k){
    int li = l + k - 3;
    if (li >= 0){
      float4 v = *(const float4*)&xin[((size_t)(b*LSEQ+li))*DINNER + e4];
      acc[0] += v.x * cw[(e4+0)*4 + k];
      acc[1] += v.y * cw[(e4+1)*4 + k];
      acc[2] += v.z * cw[(e4+2)*4 + k];
      acc[3] += v.w * cw[(e4+3)*4 + k];
    }
  }
  u32 lo = (u32)f2bf(siluf(acc[0])) | ((u32)f2bf(siluf(acc[1])) << 16);
  u32 hi = (u32)f2bf(siluf(acc[2])) | ((u32)f2bf(siluf(acc[3])) << 16);
  *(uint2*)&xc[(size_t)m*DINNER + e4] = make_uint2(lo, hi);
}

// ---------------- K4: x_proj bf16 MFMA GEMM ----------------
// dbl[m][g] = sum_k xc[m][k] * Wxp[g][k]; M=4096, N=64, K=1024. 64x64 tile, BK=64.
__global__ __launch_bounds__(256) void k4_xproj_mfma(
    const u16* __restrict__ xcbf, const u16* __restrict__ wxpb, float* __restrict__ dbl){
  __shared__ u16 As[2][4096];
  __shared__ u16 Bs[2][4096];
  int t = threadIdx.x;
  int wid = t >> 6, lane = t & 63;
  int m0 = blockIdx.x * 64;
  int wr = wid >> 1, wc = wid & 1;
  int lr = lane & 15, q = lane >> 4;

  const u16* gA = xcbf + (size_t)(m0 + (t>>2))*DINNER + (t&3)*8;
  const u16* gB = wxpb + (size_t)(t>>2)*DINNER + (t&3)*8;

  f32x4 acc[2][2];
  #pragma unroll
  for (int i=0;i<2;++i)
    #pragma unroll
    for (int j=0;j<2;++j) acc[i][j] = (f32x4){0.f,0.f,0.f,0.f};

  #pragma unroll
  for (int r=0;r<2;++r){
    gld16(gA + r*32, &As[0][(r*256 + wid*64)*8]);
    gld16(gB + r*32, &Bs[0][(r*256 + wid*64)*8]);
  }
  const int abase = (wr*32 + lr)*32 + q*8;
  const int bbase = (wc*32 + lr)*32 + q*8;

  for (int ks = 0; ks < 16; ++ks){
    int cur = ks & 1;
    __syncthreads();
    if (ks < 15){
      const u16* gA2 = gA + (ks+1)*64;
      const u16* gB2 = gB + (ks+1)*64;
      #pragma unroll
      for (int r=0;r<2;++r){
        gld16(gA2 + r*32, &As[cur^1][(r*256 + wid*64)*8]);
        gld16(gB2 + r*32, &Bs[cur^1][(r*256 + wid*64)*8]);
      }
    }
    bf16x8 a[2][2], bv[2][2];
    #pragma unroll
    for (int mf=0; mf<2; ++mf)
      #pragma unroll
      for (int s=0; s<2; ++s) a[mf][s] = *(const bf16x8*)&As[cur][abase + mf*512 + s*2048];
    #pragma unroll
    for (int nf=0; nf<2; ++nf)
      #pragma unroll
      for (int s=0; s<2; ++s) bv[nf][s] = *(const bf16x8*)&Bs[cur][bbase + nf*512 + s*2048];
    #pragma unroll
    for (int s=0; s<2; ++s)
      #pragma unroll
      for (int mf=0; mf<2; ++mf)
        #pragma unroll
        for (int nf=0; nf<2; ++nf)
          acc[mf][nf] = __builtin_amdgcn_mfma_f32_16x16x32_bf16(a[mf][s], bv[nf][s], acc[mf][nf], 0, 0, 0);
  }

  #pragma unroll
  for (int mf=0; mf<2; ++mf){
    int rowb = m0 + wr*32 + mf*16 + q*4;
    #pragma unroll
    for (int nf=0; nf<2; ++nf){
      f32x4 v = acc[mf][nf];
      int col = wc*32 + nf*16 + lr;
      #pragma unroll
      for (int j=0;j<4;++j) dbl[(size_t)(rowb+j)*GDBL + col] = v[j];
    }
  }
}

// ---------------- K6a: chunk-local scan (dt_proj fused), h0 = 0 ----------------
__global__ __launch_bounds__(256) void k6a_scanlocal(
    const float* __restrict__ dblg, const u16* __restrict__ xcg,
    const float* __restrict__ Wdt, const float* __restrict__ dtbias,
    const float* __restrict__ Alog, const float* __restrict__ Dp,
    float* __restrict__ ypart, float* __restrict__ Scum,
    float* __restrict__ hend, float* __restrict__ dchunk){
  int blk = blockIdx.x;
  int b = blk >> 10;
  int slice = (blk >> 4) & 63;
  int chunk = blk & 15;
  int d0 = slice * 16;
  int t = threadIdx.x;
  int dl = t >> 4, n = t & 15;
  int d = d0 + dl;
  float Adn = -__expf(Alog[d*NST + n]);
  float Dv = Dp[d];
  float h = 0.f;
  float S = 0.f;

  __shared__ float dbls[32][36];
  __shared__ float Wdts[16][33];
  __shared__ float biass[16];
  __shared__ float dts_t[16][36];
  __shared__ float xcs_t[16][36];
  __shared__ float Bts[16][36];
  __shared__ float Cts[16][36];
  __shared__ float ys[16][33];
  __shared__ float Ss_l[16][33];

  {
    int c = t & 31, rr = t >> 5;
    Wdts[rr][c]   = Wdt[(size_t)(d0+rr)*RDT + c];
    Wdts[rr+8][c] = Wdt[(size_t)(d0+rr+8)*RDT + c];
    if (t < 16) biass[t] = dtbias[d0+t];
  }

  for (int sub = 0; sub < CHL/32; ++sub){
    int l0 = chunk*CHL + sub*32;
    __syncthreads();
    {
      int c4 = (t & 7) * 4;
      int rr = t >> 3;
      float4 v = *(const float4*)&dblg[(size_t)(b*LSEQ + l0 + rr)*GDBL + c4];
      *(float4*)&dbls[rr][c4] = v;
      int c = t & 15;
      int r1 = t >> 4, r2 = r1 + 16;
      size_t row1 = (size_t)(b*LSEQ + l0 + r1);
      size_t row2 = (size_t)(b*LSEQ + l0 + r2);
      xcs_t[c][r1] = bf2f(xcg[row1*DINNER + d0 + c]);
      xcs_t[c][r2] = bf2f(xcg[row2*DINNER + d0 + c]);
      Bts[c][r1]   = dblg[row1*GDBL + RDT + c];
      Bts[c][r2]   = dblg[row2*GDBL + RDT + c];
      Cts[c][r1]   = dblg[row1*GDBL + RDT + NST + c];
      Cts[c][r2]   = dblg[row2*GDBL + RDT + NST + c];
    }
    __syncthreads();
    {
      int c = t & 15;
      int r1 = t >> 4, r2 = r1 + 16;
      float s1 = biass[c], s2 = biass[c];
      #pragma unroll
      for (int rr=0; rr<RDT; ++rr){
        float w = Wdts[c][rr];
        s1 += dbls[r1][rr] * w;
        s2 += dbls[r2][rr] * w;
      }
      dts_t[c][r1] = softplusf(s1);
      dts_t[c][r2] = softplusf(s2);
    }
    __syncthreads();
    for (int r0=0; r0<32; r0+=4){
      float4 dt4 = *(const float4*)&dts_t[dl][r0];
      float4 xc4 = *(const float4*)&xcs_t[dl][r0];
      float4 B4  = *(const float4*)&Bts[n][r0];
      float4 C4  = *(const float4*)&Cts[n][r0];
      const float* dtp = (const float*)&dt4;
      const float* xcp = (const float*)&xc4;
      const float* Bp  = (const float*)&B4;
      const float* Cp  = (const float*)&C4;
      #pragma unroll
      for (int j=0;j<4;++j){
        int r = r0 + j;
        float dtv = dtp[j];
        float a = __expf(dtv * Adn);
        h = a*h + dtv * Bp[j] * xcp[j];
        S += dtv;
        float p = red16(h * Cp[j]);
        if (n == 0){
          ys[dl][r]   = p + xcp[j]*Dv;
          Ss_l[dl][r] = S;
        }
      }
    }
    __syncthreads();
    {
      int c = t & 31;
      int rr = t >> 5;
      size_t o1 = ((size_t)(b*DINNER + d0 + rr))*LSEQ + l0 + c;
      size_t o2 = ((size_t)(b*DINNER + d0 + rr + 8))*LSEQ + l0 + c;
      ypart[o1] = ys[rr][c];     ypart[o2] = ys[rr+8][c];
      Scum[o1]  = Ss_l[rr][c];   Scum[o2]  = Ss_l[rr+8][c];
    }
  }
  int cix = ((b*NCH + chunk)*DINNER + d)*NST + n;
  hend[cix]   = h;
  dchunk[cix] = __expf(Adn * S);
}

// ---------------- K6b: sequential combine over chunks ----------------
__global__ void k6b_combine(const float* __restrict__ hend, const float* __restrict__ dchunk,
                            float* __restrict__ h0s){
  int idx = blockIdx.x*blockDim.x + threadIdx.x;
  int b = idx >> 14;
  int r = idx & 16383;
  float h = 0.f;
  #pragma unroll
  for (int c=0; c<NCH; ++c){
    int base = ((b*NCH + c) << 14) + r;
    h0s[base] = h;
    h = dchunk[base]*h + hend[base];
  }
}

// ---------------- K6c: correction + gate, writes bf16 y (B,L,E) ----------------
__global__ __launch_bounds__(256) void k6c_fixup(
    const float* __restrict__ dblg, const float* __restrict__ zg,
    const float* __restrict__ Alog, const float* __restrict__ Scum,
    const float* __restrict__ h0s, const float* __restrict__ ypart,
    u16* __restrict__ ybf){
  int blk = blockIdx.x;
  int b = blk >> 10;
  int slice = (blk >> 4) & 63;
  int chunk = blk & 15;
  int d0 = slice * 16;
  int t = threadIdx.x;
  int dl = t >> 4, n = t & 15;
  int d = d0 + dl;
  float Adn = -__expf(Alog[d*NST + n]);
  float h0v = h0s[((size_t)(b*NCH + chunk) << 14) + (d<<4) + n];

  __shared__ float Cts[16][36];
  __shared__ float zs[32][17];
  __shared__ float Ss_s[16][36];
  __shared__ float ys_s[16][36];

  for (int sub = 0; sub < CHL/32; ++sub){
    int l0 = chunk*CHL + sub*32;
    __syncthreads();
    {
      if (t < 128){
        int dr = t >> 3, c4 = (t & 7) * 4;
        *(float4*)&Ss_s[dr][c4] = *(const float4*)&Scum[((size_t)(b*DINNER + d0 + dr))*LSEQ + l0 + c4];
      } else {
        int t2 = t - 128;
        int dr = t2 >> 3, c4 = (t2 & 7) * 4;
        *(float4*)&ys_s[dr][c4] = *(const float4*)&ypart[((size_t)(b*DINNER + d0 + dr))*LSEQ + l0 + c4];
      }
      int c = t & 15;
      int r1 = t >> 4, r2 = r1 + 16;
      size_t row1 = (size_t)(b*LSEQ + l0 + r1);
      size_t row2 = (size_t)(b*LSEQ + l0 + r2);
      Cts[c][r1] = dblg[row1*GDBL + RDT + NST + c];
      Cts[c][r2] = dblg[row2*GDBL + RDT + NST + c];
      zs[r1][c]  = zg[row1*DINNER + d0 + c];
      zs[r2][c]  = zg[row2*DINNER + d0 + c];
    }
    __syncthreads();
    for (int r0=0; r0<32; r0+=4){
      float4 S4 = *(const float4*)&Ss_s[dl][r0];
      float4 C4 = *(const float4*)&Cts[n][r0];
      const float* Sp = (const float*)&S4;
      const float* Cp = (const float*)&C4;
      #pragma unroll
      for (int j=0;j<4;++j){
        int r = r0 + j;
        float e = __expf(Adn * Sp[j]);
        float p = red16(Cp[j] * e * h0v);
        if (n == 0){
          ys_s[dl][r] = (ys_s[dl][r] + p) * siluf(zs[r][dl]);
        }
      }
    }
    __syncthreads();
    { // write bf16 y chunk, (B,L,E) layout: 2 bf16 per thread
      int r = t >> 3, pr = t & 7;
      float v0 = ys_s[pr*2][r];
      float v1 = ys_s[pr*2+1][r];
      u32 u = (u32)f2bf(v0) | ((u32)f2bf(v1) << 16);
      *(u32*)&ybf[((size_t)(b*LSEQ + l0 + r))*DINNER + d0 + pr*2] = u;
    }
  }
}

// ---------------- K7: out_proj bf16 MFMA GEMM ----------------
__global__ __launch_bounds__(256) void k7_outproj_mfma(
    const u16* __restrict__ ybf, const u16* __restrict__ wopb, float* __restrict__ xm){
  __shared__ u16 As[2][4096];
  __shared__ u16 Bs[2][4096];
  int t = threadIdx.x;
  int wid = t >> 6, lane = t & 63;
  int n0 = blockIdx.x * 64, m0 = blockIdx.y * 64;
  int wr = wid >> 1, wc = wid & 1;
  int lr = lane & 15, q = lane >> 4;

  const u16* gA = ybf  + (size_t)(m0 + (t>>2))*DINNER + (t&3)*8;
  const u16* gB = wopb + (size_t)(n0 + (t>>2))*DINNER + (t&3)*8;

  f32x4 acc[2][2];
  #pragma unroll
  for (int i=0;i<2;++i)
    #pragma unroll
    for (int j=0;j<2;++j) acc[i][j] = (f32x4){0.f,0.f,0.f,0.f};

  #pragma unroll
  for (int r=0;r<2;++r){
    gld16(gA + r*32, &As[0][(r*256 + wid*64)*8]);
    gld16(gB + r*32, &Bs[0][(r*256 + wid*64)*8]);
  }
  const int abase = (wr*32 + lr)*32 + q*8;
  const int bbase = (wc*32 + lr)*32 + q*8;

  for (int ks = 0; ks < 16; ++ks){
    int cur = ks & 1;
    __syncthreads();
    if (ks < 15){
      const u16* gA2 = gA + (ks+1)*64;
      const u16* gB2 = gB + (ks+1)*64;
      #pragma unroll
      for (int r=0;r<2;++r){
        gld16(gA2 + r*32, &As[cur^1][(r*256 + wid*64)*8]);
        gld16(gB2 + r*32, &Bs[cur^1][(r*256 + wid*64)*8]);
      }
    }
    bf16x8 a[2][2], bv[2][2];
    #pragma unroll
    for (int mf=0; mf<2; ++mf)
      #pragma unroll
      for (int s=0; s<2; ++s) a[mf][s] = *(const bf16x8*)&As[cur][abase + mf*512 + s*2048];
    #pragma unroll
    for (int nf=0; nf<2; ++nf)
      #pragma unroll
      for (int s=0; s<2; ++s) bv[nf][s] = *(const bf16x8*)&Bs[cur][bbase + nf*512 + s*2048];
    #pragma unroll
    for (int s=0; s<2; ++s)
      #pragma unroll
      for (int mf=0; mf<2; ++mf)
        #pragma unroll
        for (int nf=0; nf<2; ++nf)
          acc[mf][nf] = __builtin_amdgcn_mfma_f32_16x16x32_bf16(a[mf][s], bv[nf][s], acc[mf][nf], 0, 0, 0);
  }

  #pragma unroll
  for (int mf=0; mf<2; ++mf){
    int rowb = m0 + wr*32 + mf*16 + q*4;
    #pragma unroll
    for (int nf=0; nf<2; ++nf){
      f32x4 v = acc[mf][nf];
      int col = n0 + wc*32 + nf*16 + lr;
      #pragma unroll
      for (int j=0;j<4;++j) xm[(size_t)(rowb+j)*DMODEL + col] = v[j];
    }
  }
}

// ---------------- K8: LN2 stats over (x + xm) ----------------
__global__ void k8_ln2_stats(const float* __restrict__ x, const float* __restrict__ xm,
                             float* __restrict__ mu2, float* __restrict__ rs2){
  int blk = blockIdx.x;
  int b = blk / (LSEQ/32);
  int l0 = (blk % (LSEQ/32)) * 32;
  int t = threadIdx.x;
  int lc = t & 31, dc = t >> 5;
  const float* xb = x + (size_t)b*DMODEL*LSEQ;
  const float* xmr = xm + ((size_t)(b*LSEQ + l0 + lc))*DMODEL;
  float s=0.f, q=0.f;
  for (int d = dc*64; d < dc*64+64; ++d){
    float v = xb[(size_t)d*LSEQ + l0 + lc] + xmr[d];
    s += v; q += v*v;
  }
  __shared__ float ss[8][33], qq[8][33];
  ss[dc][lc]=s; qq[dc][lc]=q;
  __syncthreads();
  if (t < 32){
    float S=0.f,Q=0.f;
    for (int i=0;i<8;++i){S+=ss[i][t];Q+=qq[i][t];}
    float m = S/DMODEL;
    float var = Q/DMODEL - m*m;
    mu2[b*LSEQ+l0+t]=m;
    rs2[b*LSEQ+l0+t]=rsqrtf(var+1e-5f);
  }
}

// ---------------- K9: final LN apply + transpose to (B, DIM, L) ----------------
__global__ void k9_final(const float* __restrict__ x, const float* __restrict__ xm,
                         const float* __restrict__ mu2, const float* __restrict__ rs2,
                         const float* __restrict__ w2, const float* __restrict__ b2,
                         float* __restrict__ out){
  __shared__ float s[64][65];
  int blk = blockIdx.x;
  int lt = blk & 31; int dti = (blk>>5) & 7; int b = blk >> 8;
  int l0 = lt*64, d0 = dti*64;
  int t = threadIdx.x;
  for (int rr=0; rr<64; rr+=16){
    int r = rr + (t>>4);
    float4 v = *(const float4*)&xm[((size_t)(b*LSEQ + l0 + r))*DMODEL + d0 + (t&15)*4];
    int c = (t&15)*4;
    s[r][c+0]=v.x; s[r][c+1]=v.y; s[r][c+2]=v.z; s[r][c+3]=v.w;
  }
  __syncthreads();
  int lc = t & 63;
  int drb = (t>>6)*16;
  #pragma unroll
  for (int i=0;i<16;++i){
    int dr = drb + i;
    int dd = d0 + dr; int l = l0 + lc;
    float v = x[((size_t)(b*DMODEL + dd))*LSEQ + l] + s[lc][dr];
    float o = (v - mu2[b*LSEQ+l]) * rs2[b*LSEQ+l] * w2[dd] + b2[dd];
    out[((size_t)(b*DMODEL+dd))*LSEQ + l] = o;
  }
}

extern "C" void kernel_launch(void* const* d_in, const int* in_sizes, int n_in,
                              void* d_out, int out_size, void* d_ws, size_t ws_size,
                              hipStream_t stream) {
  const float* x      = (const float*)d_in[0];
  const float* n1w    = (const float*)d_in[1];
  const float* n1b    = (const float*)d_in[2];
  const float* n2w    = (const float*)d_in[3];
  const float* n2b    = (const float*)d_in[4];
  const float* Wip    = (const float*)d_in[5];
  const float* cw     = (const float*)d_in[6];
  const float* cb     = (const float*)d_in[7];
  const float* Wxp    = (const float*)d_in[8];
  const float* Wdt    = (const float*)d_in[9];
  const float* dtbias = (const float*)d_in[10];
  const float* Alog   = (const float*)d_in[11];
  const float* Dp     = (const float*)d_in[12];
  const float* Wop    = (const float*)d_in[13];
  float* out = (float*)d_out;

  // Workspace layout (floats), ~75.8 MB total:
  float* ws   = (float*)d_ws;
  float* mu2  = ws;                      // 4096
  float* rs2  = ws + 4096;               // 4096
  float* xin  = ws + 16384;              // (B,L,E) fp32; later ypart (B,E,L)
  float* zb   = xin + 4194304;           // (B,L,E) fp32; later xm (B,L,DIM)
  float* reg3 = zb + 4194304;            // 16MB region: xnb bf16 / xcb bf16 (lo 8MB) + ybf bf16 (hi 8MB)
  float* dbl  = reg3 + 4194304;          // (B,L,64)
  float* Scum = dbl + 262144;            // (B,E,L) fp32; earlier wipb bf16
  float* hend = Scum + 4194304;          // (B,NCH,E,NST)
  float* dchk = hend + 524288;
  float* h0s  = dchk + 524288;
  u16*  wopb  = (u16*)(h0s + 524288);    // 512*1024 bf16 (262144 floats)
  u16*  wxpb  = (u16*)(h0s + 524288 + 262144);  // 64*1024 bf16

  u16*  xnb  = (u16*)reg3;               // (B,L,D) bf16  (dead after k2)
  u16*  xcb  = (u16*)reg3;               // (B,L,E) bf16  (k3..k6a; overwrites dead xnb)
  u16*  ybf  = (u16*)reg3 + 4194304;     // (B,L,E) bf16  (k6c..k7; hi half of reg3)
  u16*  wipb = (u16*)Scum;               // (2048,512) bf16 (dead before k6a writes Scum)
  float* ypart = xin;
  float* xm    = zb;

  k0_wcvt      <<<dim3(1600),        dim3(256), 0, stream>>>(Wip, Wop, Wxp, wipb, wopb, wxpb);
  k1_ln_norm   <<<dim3(BSZ*64),      dim3(256), 0, stream>>>(x, n1w, n1b, xnb);
  k2_inproj_mfma<<<dim3(16,32),      dim3(256), 0, stream>>>(xnb, wipb, xin, zb);
  k3_conv      <<<dim3(4096),        dim3(256), 0, stream>>>(xin, cw, cb, xcb);
  k4_xproj_mfma<<<dim3(64),          dim3(256), 0, stream>>>(xcb, wxpb, dbl);
  k6a_scanlocal<<<dim3(BSZ*64*NCH),  dim3(256), 0, stream>>>(dbl, xcb, Wdt, dtbias, Alog, Dp, ypart, Scum, hend, dchk);
  k6b_combine  <<<dim3(128),         dim3(256), 0, stream>>>(hend, dchk, h0s);
  k6c_fixup    <<<dim3(BSZ*64*NCH),  dim3(256), 0, stream>>>(dbl, zb, Alog, Scum, h0s, ypart, ybf);
  k7_outproj_mfma<<<dim3(8,64),      dim3(256), 0, stream>>>(ybf, wopb, xm);
  k8_ln2_stats <<<dim3(BSZ*(LSEQ/32)), dim3(256), 0, stream>>>(x, xm, mu2, rs2);
  k9_final     <<<dim3(512),         dim3(256), 0, stream>>>(x, xm, mu2, rs2, n2w, n2b, out);
}